// Round 17
// baseline (122.261 us; speedup 1.0000x reference)
//
#include <hip/hip_runtime.h>
#include <cmath>

#define B_ 2
#define N_ 2048
#define D_ 1024
#define H_ 16

typedef __attribute__((ext_vector_type(8))) short short8;
typedef __attribute__((ext_vector_type(4))) float f32x4;
typedef __attribute__((ext_vector_type(4))) unsigned short u16x4;
typedef __attribute__((ext_vector_type(4))) unsigned int uint4v;

__device__ __forceinline__ unsigned short f2bf(float f) {
    union { float f; unsigned u; } x;
    x.f = f;
    unsigned r = x.u + 0x7FFFu + ((x.u >> 16) & 1u);
    return (unsigned short)(r >> 16);
}
__device__ __forceinline__ float bf2f(unsigned short u) {
    union { unsigned u; float f; } x;
    x.u = ((unsigned)u) << 16;
    return x.f;
}
__device__ __forceinline__ unsigned cvt_pk_bf16(float lo, float hi) {
    unsigned r;
    asm("v_cvt_pk_bf16_f32 %0, %1, %2" : "=v"(r) : "v"(lo), "v"(hi));
    return r;
}
__device__ __forceinline__ float exp2_fast(float x) {
    float r;
    asm("v_exp_f32 %0, %1" : "=v"(r) : "v"(x));
    return r;
}
__device__ __forceinline__ void gload_lds16(const void* g, void* l) {
    __builtin_amdgcn_global_load_lds((const __attribute__((address_space(1))) unsigned*)g,
                                     (__attribute__((address_space(3))) unsigned*)l,
                                     16, 0, 0);
}

// ---------------- cos/sin tables ----------------
__global__ __launch_bounds__(256) void freqtab_kernel(const float* __restrict__ pos,
                                                      float2* __restrict__ tabq,
                                                      float2* __restrict__ tabk) {
    const int idx = blockIdx.x * 256 + threadIdx.x;
    const float f = pos[idx];
    const float cc = cosf(f), ss = sinf(f);
    const float sq = 0.125f * 1.4426950408889634f;
    tabq[idx] = make_float2(sq * cc, sq * ss);
    tabk[idx] = make_float2(cc, ss);
}

// ---------------- RMS-like norm ----------------
__global__ __launch_bounds__(256) void rmsnorm_kernel(const float* __restrict__ x,
                                                      unsigned short* __restrict__ xb,
                                                      float* __restrict__ s) {
    const int row = blockIdx.x;
    const float4 v = reinterpret_cast<const float4*>(x + (size_t)row * D_)[threadIdx.x];
    float ss = v.x * v.x + v.y * v.y + v.z * v.z + v.w * v.w;
    #pragma unroll
    for (int off = 32; off; off >>= 1) ss += __shfl_xor(ss, off, 64);
    __shared__ float wss[4];
    if ((threadIdx.x & 63) == 0) wss[threadIdx.x >> 6] = ss;
    __syncthreads();
    const float tot = wss[0] + wss[1] + wss[2] + wss[3];
    const float inv = 1.0f / fmaxf(sqrtf(tot * (1.0f / D_)), 1e-8f);
    if (threadIdx.x == 0) s[row] = inv;
    u16x4 ox;
    ox[0] = f2bf(v.x); ox[1] = f2bf(v.y); ox[2] = f2bf(v.z); ox[3] = f2bf(v.w);
    *reinterpret_cast<u16x4*>(xb + (size_t)row * D_ + threadIdx.x * 4) = ox;
}

// ---------------- weight transposes (gamma folded into Wq) ----------------
__global__ __launch_bounds__(256) void convT_all_kernel(const float* __restrict__ Wq,
                                                        const float* __restrict__ Wkv,
                                                        const float* __restrict__ Wo,
                                                        const float* __restrict__ gamma,
                                                        unsigned short* __restrict__ Wqt,
                                                        unsigned short* __restrict__ Wkvt,
                                                        unsigned short* __restrict__ Wot) {
    __shared__ float tile[32][33];
    const int bx = blockIdx.x;
    const float* W;
    unsigned short* Wt;
    int Nm, n0;
    bool gmul = false;
    if (bx < 32)       { W = Wq;  Wt = Wqt;  Nm = 1024; n0 = bx * 32; gmul = true; }
    else if (bx < 96)  { W = Wkv; Wt = Wkvt; Nm = 2048; n0 = (bx - 32) * 32; }
    else               { W = Wo;  Wt = Wot;  Nm = 1024; n0 = (bx - 96) * 32; }
    const int k0 = blockIdx.y * 32;
    const int r = threadIdx.x >> 3, c4 = (threadIdx.x & 7) * 4;
    const float4 ld = *reinterpret_cast<const float4*>(W + (size_t)(k0 + r) * Nm + n0 + c4);
    tile[r][c4 + 0] = ld.x; tile[r][c4 + 1] = ld.y;
    tile[r][c4 + 2] = ld.z; tile[r][c4 + 3] = ld.w;
    __syncthreads();
    u16x4 o;
    #pragma unroll
    for (int j = 0; j < 4; ++j) {
        float v = tile[c4 + j][r];
        if (gmul) v *= gamma[k0 + c4 + j];
        o[j] = f2bf(v);
    }
    *reinterpret_cast<u16x4*>(Wt + (size_t)(n0 + r) * 1024 + k0 + c4) = o;
}

// ---------------- merged q + kv GEMM: BM=64, BN=128, BK=64, dbuf, vmcnt(6) ----------------
__global__ __launch_bounds__(256) void gemm_qkv_kernel(const unsigned short* __restrict__ xb,
                                                       const unsigned short* __restrict__ Wqt,
                                                       const unsigned short* __restrict__ Wkvt,
                                                       const float* __restrict__ s,
                                                       unsigned short* __restrict__ qb,
                                                       unsigned short* __restrict__ kb,
                                                       unsigned short* __restrict__ vt,
                                                       const float2* __restrict__ tabq,
                                                       const float2* __restrict__ tabk) {
    __shared__ unsigned short As[2][64 * 64];
    __shared__ unsigned short Bs[2][128 * 64];
    __shared__ float sld[64];
    const int bid = blockIdx.x;
    const int xcd = bid & 7;
    const int ii = bid >> 3;
    const int bx = xcd * 3 + (ii % 3);
    const int m0 = (ii / 3) * 64;

    const unsigned short* Bt;
    int n0;
    if (bx < 8)       { Bt = Wqt;  n0 = bx * 128; }
    else if (bx < 16) { Bt = Wkvt; n0 = (bx - 8) * 128; }
    else              { Bt = Wkvt; n0 = (bx - 16) * 128 + 1024; }

    const int tid = threadIdx.x, lane = tid & 63, w = tid >> 6;
    const int wm = w >> 1, wn = w & 1;
    const int cc = lane & 15;
    const int sr = tid >> 3;
    const int sc = (tid & 7) * 8;

    if (tid < 64) sld[tid] = s[m0 + tid];

    f32x4 acc[2][4] = {};

    #pragma unroll
    for (int i = 0; i < 4; ++i) {
        const int r = i * 32 + sr;
        const int cs = sc ^ ((r & 7) << 3);
        if (i < 2)
            gload_lds16(xb + (size_t)(m0 + r) * 1024 + cs, (char*)As[0] + i * 4096 + w * 1024);
        gload_lds16(Bt + (size_t)(n0 + r) * 1024 + cs, (char*)Bs[0] + i * 4096 + w * 1024);
    }

    for (int t = 0; t < 16; ++t) {
        if (t + 1 < 16) {
            const int k0 = (t + 1) * 64;
            char* ad = (char*)As[(t + 1) & 1];
            char* bd = (char*)Bs[(t + 1) & 1];
            #pragma unroll
            for (int i = 0; i < 4; ++i) {
                const int r = i * 32 + sr;
                const int cs = sc ^ ((r & 7) << 3);
                if (i < 2)
                    gload_lds16(xb + (size_t)(m0 + r) * 1024 + k0 + cs, ad + i * 4096 + w * 1024);
                gload_lds16(Bt + (size_t)(n0 + r) * 1024 + k0 + cs, bd + i * 4096 + w * 1024);
            }
            asm volatile("s_waitcnt vmcnt(6)" ::: "memory");
        } else {
            asm volatile("s_waitcnt vmcnt(0)" ::: "memory");
        }
        __builtin_amdgcn_s_barrier();

        const char* Ac = (const char*)As[t & 1];
        const char* Bc = (const char*)Bs[t & 1];

        short8 af[2][2], bf[4][2];
        #pragma unroll
        for (int mf = 0; mf < 2; ++mf)
            #pragma unroll
            for (int ks = 0; ks < 2; ++ks) {
                const int r = wm * 32 + mf * 16 + cc;
                const int cb = (ks * 64 + ((lane >> 4) * 16)) ^ ((r & 7) << 4);
                af[mf][ks] = *reinterpret_cast<const short8*>(Ac + r * 128 + cb);
            }
        #pragma unroll
        for (int nf = 0; nf < 4; ++nf)
            #pragma unroll
            for (int ks = 0; ks < 2; ++ks) {
                const int r = wn * 64 + nf * 16 + cc;
                const int cb = (ks * 64 + ((lane >> 4) * 16)) ^ ((r & 7) << 4);
                bf[nf][ks] = *reinterpret_cast<const short8*>(Bc + r * 128 + cb);
            }
        #pragma unroll
        for (int ks = 0; ks < 2; ++ks)
            #pragma unroll
            for (int mf = 0; mf < 2; ++mf)
                #pragma unroll
                for (int nf = 0; nf < 4; ++nf)
                    acc[mf][nf] = __builtin_amdgcn_mfma_f32_16x16x32_bf16(af[mf][ks], bf[nf][ks], acc[mf][nf], 0, 0, 0);

        __builtin_amdgcn_s_barrier();
    }

    if (bx < 16) {
        const float2* tab = (bx < 8) ? tabq : tabk;
        unsigned short* dst = (bx < 8) ? qb : kb;
        const bool doscale = (bx < 8);
        #pragma unroll
        for (int mf = 0; mf < 2; ++mf)
            #pragma unroll
            for (int reg = 0; reg < 4; ++reg) {
                const int rloc = wm * 32 + mf * 16 + (lane >> 4) * 4 + reg;
                const int row = m0 + rloc;
                const int n = row & (N_ - 1);
                const float srow = doscale ? sld[rloc] : 1.0f;
                #pragma unroll
                for (int nf = 0; nf < 2; ++nf) {
                    const int d = nf * 16 + cc;
                    const float2 t1 = tab[n * 64 + d];
                    const float2 t2 = tab[n * 64 + 32 + d];
                    const float x1 = acc[mf][nf][reg] * srow;
                    const float x2 = acc[mf][nf + 2][reg] * srow;
                    const float o1 = x1 * t1.x - x2 * t1.y;
                    const float o2 = x2 * t2.x + x1 * t2.y;
                    const int col = n0 + wn * 64 + nf * 16 + cc;
                    dst[(size_t)row * 1024 + col] = f2bf(o1);
                    dst[(size_t)row * 1024 + col + 32] = f2bf(o2);
                }
            }
    } else {
        // V: store transposed into vt[bh*64+d][pos], pos = within-64-tile key permutation:
        // key bits (wm, mf, gg1, gg0, reg1, reg0) -> pos = wm*32 + gg1*16 + gg0*8 + mf*4 + reg
        const int bb = m0 >> 11;
        const int gg = lane >> 4;
        const int tb = m0 & (N_ - 1);
        #pragma unroll
        for (int mf = 0; mf < 2; ++mf) {
            const int npos = tb + wm * 32 + (gg >> 1) * 16 + (gg & 1) * 8 + mf * 4;
            #pragma unroll
            for (int nf = 0; nf < 4; ++nf) {
                const int cv = n0 - 1024 + wn * 64 + nf * 16 + cc;
                const int h = cv >> 6, d = cv & 63;
                uint2 u;
                u.x = cvt_pk_bf16(acc[mf][nf][0], acc[mf][nf][1]);
                u.y = cvt_pk_bf16(acc[mf][nf][2], acc[mf][nf][3]);
                *reinterpret_cast<uint2*>(vt + ((size_t)(bb * 16 + h) * 64 + d) * 2048 + npos) = u;
            }
        }
    }
}

// ---------------- output GEMM ----------------
__global__ __launch_bounds__(256) void gemm_o_kernel(const unsigned short* __restrict__ A,
                                                     const unsigned short* __restrict__ Bt,
                                                     const float* __restrict__ bias,
                                                     float* __restrict__ Cout) {
    __shared__ unsigned short As[2][128 * 64];
    __shared__ unsigned short Bs[2][64 * 64];
    const int bid = blockIdx.x;
    const int xcd = bid & 7;
    const int ii = bid >> 3;
    const int n0 = (xcd * 2 + (ii & 1)) * 64;
    const int m0 = (ii >> 1) * 128;
    const int tid = threadIdx.x, lane = tid & 63, w = tid >> 6;
    const int wm = w >> 1, wn = w & 1;
    const int cc = lane & 15;
    const int sr = tid >> 3;
    const int sc = (tid & 7) * 8;

    f32x4 acc[4][2] = {};

    #pragma unroll
    for (int i = 0; i < 4; ++i) {
        const int r = i * 32 + sr;
        const int cs = sc ^ ((r & 7) << 3);
        gload_lds16(A + (size_t)(m0 + r) * 1024 + cs, (char*)As[0] + i * 4096 + w * 1024);
        if (i < 2)
            gload_lds16(Bt + (size_t)(n0 + r) * 1024 + cs, (char*)Bs[0] + i * 4096 + w * 1024);
    }

    for (int t = 0; t < 16; ++t) {
        if (t + 1 < 16) {
            const int k0 = (t + 1) * 64;
            char* ad = (char*)As[(t + 1) & 1];
            char* bd = (char*)Bs[(t + 1) & 1];
            #pragma unroll
            for (int i = 0; i < 4; ++i) {
                const int r = i * 32 + sr;
                const int cs = sc ^ ((r & 7) << 3);
                gload_lds16(A + (size_t)(m0 + r) * 1024 + k0 + cs, ad + i * 4096 + w * 1024);
                if (i < 2)
                    gload_lds16(Bt + (size_t)(n0 + r) * 1024 + k0 + cs, bd + i * 4096 + w * 1024);
            }
            asm volatile("s_waitcnt vmcnt(6)" ::: "memory");
        } else {
            asm volatile("s_waitcnt vmcnt(0)" ::: "memory");
        }
        __builtin_amdgcn_s_barrier();

        const char* Ac = (const char*)As[t & 1];
        const char* Bc = (const char*)Bs[t & 1];

        short8 af[4][2], bf[2][2];
        #pragma unroll
        for (int mf = 0; mf < 4; ++mf)
            #pragma unroll
            for (int ks = 0; ks < 2; ++ks) {
                const int r = wm * 64 + mf * 16 + cc;
                const int cb = (ks * 64 + ((lane >> 4) * 16)) ^ ((r & 7) << 4);
                af[mf][ks] = *reinterpret_cast<const short8*>(Ac + r * 128 + cb);
            }
        #pragma unroll
        for (int nf = 0; nf < 2; ++nf)
            #pragma unroll
            for (int ks = 0; ks < 2; ++ks) {
                const int r = wn * 32 + nf * 16 + cc;
                const int cb = (ks * 64 + ((lane >> 4) * 16)) ^ ((r & 7) << 4);
                bf[nf][ks] = *reinterpret_cast<const short8*>(Bc + r * 128 + cb);
            }
        #pragma unroll
        for (int ks = 0; ks < 2; ++ks)
            #pragma unroll
            for (int mf = 0; mf < 4; ++mf)
                #pragma unroll
                for (int nf = 0; nf < 2; ++nf)
                    acc[mf][nf] = __builtin_amdgcn_mfma_f32_16x16x32_bf16(af[mf][ks], bf[nf][ks], acc[mf][nf], 0, 0, 0);

        __builtin_amdgcn_s_barrier();
    }

    float bb[2];
    #pragma unroll
    for (int nf = 0; nf < 2; ++nf) bb[nf] = bias[n0 + wn * 32 + nf * 16 + cc];
    #pragma unroll
    for (int mf = 0; mf < 4; ++mf)
        #pragma unroll
        for (int nf = 0; nf < 2; ++nf)
            #pragma unroll
            for (int reg = 0; reg < 4; ++reg) {
                const int row = m0 + wm * 64 + mf * 16 + (lane >> 4) * 4 + reg;
                const int col = n0 + wn * 32 + nf * 16 + cc;
                Cout[(size_t)row * 1024 + col] = acc[mf][nf][reg] + bb[nf];
            }
}

// ---------------- attention: 128 threads (2 waves), wave owns 32 q-rows (2 qt) ----------------
// grid 1536, slot/split/merge mapping unchanged. K dbuf + V single (24KB LDS).
// K-frag and V-frag ds_reads shared across both qt (2 MFMA per fragment load).
__global__ __launch_bounds__(128, 3) void attn_mfma_kernel(const unsigned short* __restrict__ q,
                                                           const unsigned short* __restrict__ kb,
                                                           const unsigned short* __restrict__ vt,
                                                           unsigned short* __restrict__ att,
                                                           unsigned short* __restrict__ pO,
                                                           float2* __restrict__ pml) {
    const int bid = blockIdx.x;
    const int xcd = bid & 7;
    const int rest = bid >> 3;          // 0..191
    const int bh = xcd * 4 + rest / 48;
    const int s = 47 - (rest % 48);
    int qi, t0, t1, half;
    bool split;
    if (s < 16) {
        qi = s; t0 = 0; t1 = qi + 1; half = 0; split = false;
    } else {
        const int qs = s - 16;
        qi = 16 + (qs >> 1);
        half = qs & 1;
        const int hmid = (qi + 2) >> 1;
        t0 = half ? hmid : 0;
        t1 = half ? (qi + 1) : hmid;
        split = true;
    }
    const int b = bh >> 4, h = bh & 15;
    const int qb_ = qi * 64;
    const int tid = threadIdx.x;
    const int lane = tid & 63;
    const int w = tid >> 6;            // 0..1
    const int c = lane & 15;
    const int g = lane >> 4;

    __shared__ __align__(16) unsigned short Ks[2][64 * 64];   // 16KB
    __shared__ __align__(16) unsigned short Vs[64 * 64];      // 8KB

    // per-qt state: qrow = qb_ + w*32 + qt*16 + c
    short8 qf[2][2];
    int qrow[2];
    #pragma unroll
    for (int qt = 0; qt < 2; ++qt) {
        qrow[qt] = qb_ + w * 32 + qt * 16 + c;
        const unsigned short* qp = q + (size_t)(b * N_ + qrow[qt]) * 1024 + h * 64 + g * 8;
        qf[qt][0] = *reinterpret_cast<const short8*>(qp);
        qf[qt][1] = *reinterpret_cast<const short8*>(qp + 32);
    }

    float m[2] = {-1e30f, -1e30f}, l[2] = {0.f, 0.f};
    f32x4 oacc[2][4] = {};

    const int sr = tid >> 3, sc = (tid & 7) * 8;   // sr 0..15
    const unsigned short* kbase = kb + (size_t)b * N_ * 1024 + h * 64;
    const unsigned short* vbase = vt + (size_t)bh * 64 * 2048;

    // prologue: 4 staging calls per wave (rows i*16 + w*8 + (sr&7))
    #pragma unroll
    for (int i = 0; i < 4; ++i) {
        const int r = i * 16 + sr;
        const int cs = sc ^ ((r & 7) << 3);
        gload_lds16(kbase + (size_t)(t0 * 64 + r) * 1024 + cs,
                    (char*)Ks[t0 & 1] + i * 2048 + w * 1024);
        gload_lds16(vbase + (size_t)r * 2048 + t0 * 64 + cs,
                    (char*)Vs + i * 2048 + w * 1024);
    }

    for (int t = t0; t < t1; ++t) {
        const int jb = t * 64;
        const int jn = jb + 64;
        if (t + 1 < t1) {
            char* kd = (char*)Ks[(t + 1) & 1];
            #pragma unroll
            for (int i = 0; i < 4; ++i) {
                const int r = i * 16 + sr;
                const int cs = sc ^ ((r & 7) << 3);
                gload_lds16(kbase + (size_t)(jn + r) * 1024 + cs, kd + i * 2048 + w * 1024);
            }
            asm volatile("s_waitcnt vmcnt(4)" ::: "memory");  // K[t],V[t] landed; K[t+1] (4) flying
        } else {
            asm volatile("s_waitcnt vmcnt(0)" ::: "memory");
        }
        __builtin_amdgcn_s_barrier();

        const char* Ksc = (const char*)Ks[t & 1];
        const char* Vsc = (const char*)Vs;

        // QK^T for both qt, K-fragment loaded once per (ct,ks)
        f32x4 st[2][4];
        #pragma unroll
        for (int qt = 0; qt < 2; ++qt)
            #pragma unroll
            for (int ct = 0; ct < 4; ++ct) st[qt][ct] = f32x4{0.f, 0.f, 0.f, 0.f};
        __builtin_amdgcn_s_setprio(1);
        #pragma unroll
        for (int ct = 0; ct < 4; ++ct) {
            const int key = ct * 16 + c;
            #pragma unroll
            for (int ks = 0; ks < 2; ++ks) {
                const int addr = (key * 128 + ks * 64 + g * 16) ^ ((key & 7) << 4);
                const short8 kf = *reinterpret_cast<const short8*>(Ksc + addr);
                st[0][ct] = __builtin_amdgcn_mfma_f32_16x16x32_bf16(kf, qf[0][ks], st[0][ct], 0, 0, 0);
                st[1][ct] = __builtin_amdgcn_mfma_f32_16x16x32_bf16(kf, qf[1][ks], st[1][ct], 0, 0, 0);
            }
        }
        __builtin_amdgcn_s_setprio(0);

        // softmax + in-register P per qt
        short8 pf[2][2];
        bool act[2];
        #pragma unroll
        for (int qt = 0; qt < 2; ++qt) {
            act[qt] = (jb <= qb_ + w * 32 + qt * 16 + 15);
            if (!act[qt]) continue;
            float mx = -1e30f;
            if (jb + 63 > qrow[qt]) {
                #pragma unroll
                for (int ct = 0; ct < 4; ++ct)
                    #pragma unroll
                    for (int reg = 0; reg < 4; ++reg) {
                        const int key = jb + ct * 16 + g * 4 + reg;
                        const float sv = (key <= qrow[qt]) ? st[qt][ct][reg] : -1e30f;
                        st[qt][ct][reg] = sv;
                        mx = fmaxf(mx, sv);
                    }
            } else {
                #pragma unroll
                for (int ct = 0; ct < 4; ++ct)
                    mx = fmaxf(mx, fmaxf(fmaxf(st[qt][ct][0], st[qt][ct][1]),
                                         fmaxf(st[qt][ct][2], st[qt][ct][3])));
            }
            mx = fmaxf(mx, __shfl_xor(mx, 16, 64));
            mx = fmaxf(mx, __shfl_xor(mx, 32, 64));
            if (!__all(mx <= m[qt] + 8.0f)) {
                const float mn = fmaxf(m[qt], mx);
                const float corr = exp2_fast(m[qt] - mn);
                l[qt] *= corr;
                m[qt] = mn;
                #pragma unroll
                for (int dt = 0; dt < 4; ++dt) {
                    oacc[qt][dt][0] *= corr; oacc[qt][dt][1] *= corr;
                    oacc[qt][dt][2] *= corr; oacc[qt][dt][3] *= corr;
                }
            }
            float rs = 0.f;
            #pragma unroll
            for (int ct = 0; ct < 4; ++ct)
                #pragma unroll
                for (int reg = 0; reg < 4; ++reg) {
                    const float p = exp2_fast(st[qt][ct][reg] - m[qt]);
                    st[qt][ct][reg] = p;
                    rs += p;
                }
            rs += __shfl_xor(rs, 16, 64);
            rs += __shfl_xor(rs, 32, 64);
            l[qt] += rs;

            uint4v pv0, pv1;
            pv0[0] = cvt_pk_bf16(st[qt][0][0], st[qt][0][1]);
            pv0[1] = cvt_pk_bf16(st[qt][0][2], st[qt][0][3]);
            pv0[2] = cvt_pk_bf16(st[qt][1][0], st[qt][1][1]);
            pv0[3] = cvt_pk_bf16(st[qt][1][2], st[qt][1][3]);
            pv1[0] = cvt_pk_bf16(st[qt][2][0], st[qt][2][1]);
            pv1[1] = cvt_pk_bf16(st[qt][2][2], st[qt][2][3]);
            pv1[2] = cvt_pk_bf16(st[qt][3][0], st[qt][3][1]);
            pv1[3] = cvt_pk_bf16(st[qt][3][2], st[qt][3][3]);
            pf[qt][0] = *reinterpret_cast<const short8*>(&pv0);
            pf[qt][1] = *reinterpret_cast<const short8*>(&pv1);
        }

        // PV for both qt, V-fragment loaded once per (dt,ks)
        __builtin_amdgcn_s_setprio(1);
        #pragma unroll
        for (int dt = 0; dt < 4; ++dt) {
            const int vd = dt * 16 + c;
            #pragma unroll
            for (int ks = 0; ks < 2; ++ks) {
                const int addr = (vd * 128 + ks * 64 + g * 16) ^ ((vd & 7) << 4);
                const short8 vf = *reinterpret_cast<const short8*>(Vsc + addr);
                if (act[0])
                    oacc[0][dt] = __builtin_amdgcn_mfma_f32_16x16x32_bf16(vf, pf[0][ks], oacc[0][dt], 0, 0, 0);
                if (act[1])
                    oacc[1][dt] = __builtin_amdgcn_mfma_f32_16x16x32_bf16(vf, pf[1][ks], oacc[1][dt], 0, 0, 0);
            }
        }
        __builtin_amdgcn_s_setprio(0);

        __builtin_amdgcn_s_barrier();

        if (t + 1 < t1) {   // stage V[t+1]
            #pragma unroll
            for (int i = 0; i < 4; ++i) {
                const int r = i * 16 + sr;
                const int cs = sc ^ ((r & 7) << 3);
                gload_lds16(vbase + (size_t)r * 2048 + jn + cs, (char*)Vs + i * 2048 + w * 1024);
            }
        }
    }

    #pragma unroll
    for (int qt = 0; qt < 2; ++qt) {
        if (!split) {
            const float inv = 1.0f / l[qt];
            unsigned short* orow = att + (size_t)(b * N_ + qrow[qt]) * 1024 + h * 64;
            #pragma unroll
            for (int dt = 0; dt < 4; ++dt) {
                #pragma unroll
                for (int rp = 0; rp < 2; ++rp) {
                    const unsigned u = cvt_pk_bf16(oacc[qt][dt][2 * rp] * inv,
                                                   oacc[qt][dt][2 * rp + 1] * inv);
                    *reinterpret_cast<unsigned*>(orow + dt * 16 + g * 4 + rp * 2) = u;
                }
            }
        } else {
            const int slot = (bh * 16 + (qi - 16)) * 2 + half;
            const int rloc = w * 32 + qt * 16 + c;
            pml[slot * 64 + rloc] = make_float2(m[qt], l[qt]);
            unsigned short* prow = pO + (size_t)slot * 4096 + rloc * 64;
            #pragma unroll
            for (int dt = 0; dt < 4; ++dt) {
                #pragma unroll
                for (int rp = 0; rp < 2; ++rp) {
                    const unsigned u = cvt_pk_bf16(oacc[qt][dt][2 * rp], oacc[qt][dt][2 * rp + 1]);
                    *reinterpret_cast<unsigned*>(prow + dt * 16 + g * 4 + rp * 2) = u;
                }
            }
        }
    }
}

// ---------------- merge split-KV partials ----------------
__global__ __launch_bounds__(256) void attn_merge_kernel(const unsigned short* __restrict__ pO,
                                                         const float2* __restrict__ pml,
                                                         unsigned short* __restrict__ att) {
    const int blk = blockIdx.x;        // 0..511 = bh*16 + qt
    const int bh = blk >> 4;
    const int qt = blk & 15;
    const int qi = 16 + qt;
    const int b = bh >> 4, h = bh & 15;
    const int tid = threadIdx.x;
    const int row = tid >> 2;
    const int d0 = (tid & 3) * 16;
    const int slot0 = (bh * 16 + qt) * 2;
    const float2 ml0 = pml[slot0 * 64 + row];
    const float2 ml1 = pml[(slot0 + 1) * 64 + row];
    const float M = fmaxf(ml0.x, ml1.x);
    const float w0 = exp2_fast(ml0.x - M);
    const float w1 = exp2_fast(ml1.x - M);
    const float invL = 1.0f / (ml0.y * w0 + ml1.y * w1);
    const unsigned short* p0 = pO + (size_t)slot0 * 4096 + row * 64 + d0;
    const unsigned short* p1 = p0 + 4096;
    const int qrow = qi * 64 + row;
    unsigned short* orow = att + (size_t)(b * N_ + qrow) * 1024 + h * 64 + d0;
    #pragma unroll
    for (int j = 0; j < 16; j += 2) {
        const float a0 = (bf2f(p0[j]) * w0 + bf2f(p1[j]) * w1) * invL;
        const float a1 = (bf2f(p0[j + 1]) * w0 + bf2f(p1[j + 1]) * w1) * invL;
        *reinterpret_cast<unsigned*>(orow + j) = cvt_pk_bf16(a0, a1);
    }
}

extern "C" void kernel_launch(void* const* d_in, const int* in_sizes, int n_in,
                              void* d_out, int out_size, void* d_ws, size_t ws_size,
                              hipStream_t stream) {
    const float* x     = (const float*)d_in[0];
    const float* pos   = (const float*)d_in[1];
    const float* gamma = (const float*)d_in[2];
    const float* Wq    = (const float*)d_in[3];
    const float* Wkv   = (const float*)d_in[4];
    const float* Wo    = (const float*)d_in[5];
    const float* bo    = (const float*)d_in[6];
    float* out = (float*)d_out;
    char* ws = (char*)d_ws;

    const size_t MB = 1024 * 1024;
    unsigned short* kb   = (unsigned short*)(ws);             // 8 MB roped K
    unsigned short* qb   = (unsigned short*)(ws + 16 * MB);   // 8 MB roped+scaled Q
    unsigned short* att  = (unsigned short*)(ws + 24 * MB);   // 8 MB attention output
    unsigned short* xb   = (unsigned short*)(ws + 32 * MB);   // 8 MB bf16 x (dead after qkv)
    unsigned short* Wqt  = (unsigned short*)(ws + 40 * MB);   // 2 MB
    unsigned short* Wkvt = (unsigned short*)(ws + 42 * MB);   // 4 MB
    unsigned short* Wot  = (unsigned short*)(ws + 46 * MB);   // 2 MB
    unsigned short* vt   = (unsigned short*)(ws + 48 * MB);   // 8 MB V^T [bh][d][pos]
    float2* tabq         = (float2*)(ws + 56 * MB);           // 1 MB
    float2* tabk         = (float2*)(ws + 57 * MB);           // 1 MB
    float* sv            = (float*)(ws + 58 * MB);            // 16 KB
    unsigned short* pO   = (unsigned short*)(ws + 32 * MB);   // 8.4 MB (overlay)
    float2* pml          = (float2*)(ws + 40 * MB + 512 * 1024);  // 512 KB

    freqtab_kernel<<<512, 256, 0, stream>>>(pos, tabq, tabk);
    convT_all_kernel<<<dim3(128, 32), 256, 0, stream>>>(Wq, Wkv, Wo, gamma, Wqt, Wkvt, Wot);
    rmsnorm_kernel<<<B_ * N_, 256, 0, stream>>>(x, xb, sv);

    gemm_qkv_kernel<<<1536, 256, 0, stream>>>(
        xb, Wqt, Wkvt, sv, qb, kb, vt, tabq, tabk);

    attn_mfma_kernel<<<1536, 128, 0, stream>>>(qb, kb, vt, att, pO, pml);
    attn_merge_kernel<<<512, 256, 0, stream>>>(pO, pml, att);

    gemm_o_kernel<<<512, 256, 0, stream>>>(att, Wot, bo, out);
}

// Round 18
// 118.153 us; speedup vs baseline: 1.0348x; 1.0348x over previous
//
#include <hip/hip_runtime.h>
#include <cmath>

#define B_ 2
#define N_ 2048
#define D_ 1024
#define H_ 16

typedef __attribute__((ext_vector_type(8))) short short8;
typedef __attribute__((ext_vector_type(4))) float f32x4;
typedef __attribute__((ext_vector_type(4))) unsigned short u16x4;
typedef __attribute__((ext_vector_type(4))) unsigned int uint4v;

__device__ __forceinline__ unsigned short f2bf(float f) {
    union { float f; unsigned u; } x;
    x.f = f;
    unsigned r = x.u + 0x7FFFu + ((x.u >> 16) & 1u);
    return (unsigned short)(r >> 16);
}
__device__ __forceinline__ float bf2f(unsigned short u) {
    union { unsigned u; float f; } x;
    x.u = ((unsigned)u) << 16;
    return x.f;
}
__device__ __forceinline__ unsigned cvt_pk_bf16(float lo, float hi) {
    unsigned r;
    asm("v_cvt_pk_bf16_f32 %0, %1, %2" : "=v"(r) : "v"(lo), "v"(hi));
    return r;
}
__device__ __forceinline__ float exp2_fast(float x) {
    float r;
    asm("v_exp_f32 %0, %1" : "=v"(r) : "v"(x));
    return r;
}
__device__ __forceinline__ void gload_lds16(const void* g, void* l) {
    __builtin_amdgcn_global_load_lds((const __attribute__((address_space(1))) unsigned*)g,
                                     (__attribute__((address_space(3))) unsigned*)l,
                                     16, 0, 0);
}

// ---------------- cos/sin tables (trig once; q table pre-scaled by 0.125*log2e) ----------------
__global__ __launch_bounds__(256) void freqtab_kernel(const float* __restrict__ pos,
                                                      float2* __restrict__ tabq,
                                                      float2* __restrict__ tabk) {
    const int idx = blockIdx.x * 256 + threadIdx.x;   // N_*64 = 131072
    const float f = pos[idx];
    const float cc = cosf(f), ss = sinf(f);
    const float sq = 0.125f * 1.4426950408889634f;    // DH^-0.5 * log2(e)
    tabq[idx] = make_float2(sq * cc, sq * ss);
    tabk[idx] = make_float2(cc, ss);
}

// ---------------- RMS-like norm: emit bf16 x copy + per-row scale s ----------------
__global__ __launch_bounds__(256) void rmsnorm_kernel(const float* __restrict__ x,
                                                      unsigned short* __restrict__ xb,
                                                      float* __restrict__ s) {
    const int row = blockIdx.x;
    const float4 v = reinterpret_cast<const float4*>(x + (size_t)row * D_)[threadIdx.x];
    float ss = v.x * v.x + v.y * v.y + v.z * v.z + v.w * v.w;
    #pragma unroll
    for (int off = 32; off; off >>= 1) ss += __shfl_xor(ss, off, 64);
    __shared__ float wss[4];
    if ((threadIdx.x & 63) == 0) wss[threadIdx.x >> 6] = ss;
    __syncthreads();
    const float tot = wss[0] + wss[1] + wss[2] + wss[3];
    const float inv = 1.0f / fmaxf(sqrtf(tot * (1.0f / D_)), 1e-8f);
    if (threadIdx.x == 0) s[row] = inv;
    u16x4 ox;
    ox[0] = f2bf(v.x); ox[1] = f2bf(v.y); ox[2] = f2bf(v.z); ox[3] = f2bf(v.w);
    *reinterpret_cast<u16x4*>(xb + (size_t)row * D_ + threadIdx.x * 4) = ox;
}

// ---------------- all 3 weight transposes (gamma folded into Wq) ----------------
__global__ __launch_bounds__(256) void convT_all_kernel(const float* __restrict__ Wq,
                                                        const float* __restrict__ Wkv,
                                                        const float* __restrict__ Wo,
                                                        const float* __restrict__ gamma,
                                                        unsigned short* __restrict__ Wqt,
                                                        unsigned short* __restrict__ Wkvt,
                                                        unsigned short* __restrict__ Wot) {
    __shared__ float tile[32][33];
    const int bx = blockIdx.x;   // 0..127 over concat {Wq:32, Wkv:64, Wo:32}
    const float* W;
    unsigned short* Wt;
    int Nm, n0;
    bool gmul = false;
    if (bx < 32)       { W = Wq;  Wt = Wqt;  Nm = 1024; n0 = bx * 32; gmul = true; }
    else if (bx < 96)  { W = Wkv; Wt = Wkvt; Nm = 2048; n0 = (bx - 32) * 32; }
    else               { W = Wo;  Wt = Wot;  Nm = 1024; n0 = (bx - 96) * 32; }
    const int k0 = blockIdx.y * 32;
    const int r = threadIdx.x >> 3, c4 = (threadIdx.x & 7) * 4;
    const float4 ld = *reinterpret_cast<const float4*>(W + (size_t)(k0 + r) * Nm + n0 + c4);
    tile[r][c4 + 0] = ld.x; tile[r][c4 + 1] = ld.y;
    tile[r][c4 + 2] = ld.z; tile[r][c4 + 3] = ld.w;
    __syncthreads();
    u16x4 o;
    #pragma unroll
    for (int j = 0; j < 4; ++j) {
        float v = tile[c4 + j][r];
        if (gmul) v *= gamma[k0 + c4 + j];
        o[j] = f2bf(v);
    }
    *reinterpret_cast<u16x4*>(Wt + (size_t)(n0 + r) * 1024 + k0 + c4) = o;
}

// ---------------- merged q + kv GEMM: BM=64, BN=128, BK=64, dbuf, vmcnt(6) ----------------
// grid 1536 = 8 XCD x 3 panels x 64 m-tiles. xcd=bid&7 owns bx in [3*xcd, 3*xcd+3).
// bx 0-7: q -> qb (rope tabq, s-scaled); 8-15: K -> kb (rope tabk);
// 16-23: V -> vt with within-64-tile KEY PERMUTATION p: p4=k3,p3=k2,p2=k4 (low 2 bits kept)
// so attention's PV B-operand is lane-local (see attn kernel).
__global__ __launch_bounds__(256) void gemm_qkv_kernel(const unsigned short* __restrict__ xb,
                                                       const unsigned short* __restrict__ Wqt,
                                                       const unsigned short* __restrict__ Wkvt,
                                                       const float* __restrict__ s,
                                                       unsigned short* __restrict__ qb,
                                                       unsigned short* __restrict__ kb,
                                                       unsigned short* __restrict__ vt,
                                                       const float2* __restrict__ tabq,
                                                       const float2* __restrict__ tabk) {
    __shared__ unsigned short As[2][64 * 64];    // 8KB each
    __shared__ unsigned short Bs[2][128 * 64];   // 16KB each
    __shared__ float sld[64];
    const int bid = blockIdx.x;
    const int xcd = bid & 7;
    const int ii = bid >> 3;                 // 0..191
    const int bx = xcd * 3 + (ii % 3);       // 0..23
    const int m0 = (ii / 3) * 64;            // 0..4032

    const unsigned short* Bt;
    int n0;
    if (bx < 8)       { Bt = Wqt;  n0 = bx * 128; }
    else if (bx < 16) { Bt = Wkvt; n0 = (bx - 8) * 128; }
    else              { Bt = Wkvt; n0 = (bx - 16) * 128 + 1024; }

    const int tid = threadIdx.x, lane = tid & 63, w = tid >> 6;
    const int wm = w >> 1, wn = w & 1;       // wave tile 32 x 64
    const int cc = lane & 15;
    const int sr = tid >> 3;                 // 0..31
    const int sc = (tid & 7) * 8;

    if (tid < 64) sld[tid] = s[m0 + tid];

    f32x4 acc[2][4] = {};

    // prologue: stage K-step 0 into buf 0 (A: 2 units of 32 rows; B: 4 units)
    #pragma unroll
    for (int i = 0; i < 4; ++i) {
        const int r = i * 32 + sr;
        const int cs = sc ^ ((r & 7) << 3);
        if (i < 2)
            gload_lds16(xb + (size_t)(m0 + r) * 1024 + cs, (char*)As[0] + i * 4096 + w * 1024);
        gload_lds16(Bt + (size_t)(n0 + r) * 1024 + cs, (char*)Bs[0] + i * 4096 + w * 1024);
    }

    for (int t = 0; t < 16; ++t) {
        if (t + 1 < 16) {
            const int k0 = (t + 1) * 64;
            char* ad = (char*)As[(t + 1) & 1];
            char* bd = (char*)Bs[(t + 1) & 1];
            #pragma unroll
            for (int i = 0; i < 4; ++i) {
                const int r = i * 32 + sr;
                const int cs = sc ^ ((r & 7) << 3);
                if (i < 2)
                    gload_lds16(xb + (size_t)(m0 + r) * 1024 + k0 + cs, ad + i * 4096 + w * 1024);
                gload_lds16(Bt + (size_t)(n0 + r) * 1024 + k0 + cs, bd + i * 4096 + w * 1024);
            }
            asm volatile("s_waitcnt vmcnt(6)" ::: "memory");  // this step landed; next 6 flying
        } else {
            asm volatile("s_waitcnt vmcnt(0)" ::: "memory");
        }
        __builtin_amdgcn_s_barrier();

        const char* Ac = (const char*)As[t & 1];
        const char* Bc = (const char*)Bs[t & 1];

        short8 af[2][2], bf[4][2];
        #pragma unroll
        for (int mf = 0; mf < 2; ++mf)
            #pragma unroll
            for (int ks = 0; ks < 2; ++ks) {
                const int r = wm * 32 + mf * 16 + cc;
                const int cb = (ks * 64 + ((lane >> 4) * 16)) ^ ((r & 7) << 4);
                af[mf][ks] = *reinterpret_cast<const short8*>(Ac + r * 128 + cb);
            }
        #pragma unroll
        for (int nf = 0; nf < 4; ++nf)
            #pragma unroll
            for (int ks = 0; ks < 2; ++ks) {
                const int r = wn * 64 + nf * 16 + cc;
                const int cb = (ks * 64 + ((lane >> 4) * 16)) ^ ((r & 7) << 4);
                bf[nf][ks] = *reinterpret_cast<const short8*>(Bc + r * 128 + cb);
            }
        #pragma unroll
        for (int ks = 0; ks < 2; ++ks)
            #pragma unroll
            for (int mf = 0; mf < 2; ++mf)
                #pragma unroll
                for (int nf = 0; nf < 4; ++nf)
                    acc[mf][nf] = __builtin_amdgcn_mfma_f32_16x16x32_bf16(af[mf][ks], bf[nf][ks], acc[mf][nf], 0, 0, 0);

        __builtin_amdgcn_s_barrier();   // all waves done with buf[t&1] before overwrite
    }

    if (bx < 16) {
        // rope epilogue; q additionally scaled by per-row s (f32). Head = 64-col span (wn half).
        const float2* tab = (bx < 8) ? tabq : tabk;
        unsigned short* dst = (bx < 8) ? qb : kb;
        const bool doscale = (bx < 8);
        #pragma unroll
        for (int mf = 0; mf < 2; ++mf)
            #pragma unroll
            for (int reg = 0; reg < 4; ++reg) {
                const int rloc = wm * 32 + mf * 16 + (lane >> 4) * 4 + reg;
                const int row = m0 + rloc;
                const int n = row & (N_ - 1);
                const float srow = doscale ? sld[rloc] : 1.0f;
                #pragma unroll
                for (int nf = 0; nf < 2; ++nf) {
                    const int d = nf * 16 + cc;
                    const float2 t1 = tab[n * 64 + d];
                    const float2 t2 = tab[n * 64 + 32 + d];
                    const float x1 = acc[mf][nf][reg] * srow;
                    const float x2 = acc[mf][nf + 2][reg] * srow;
                    const float o1 = x1 * t1.x - x2 * t1.y;
                    const float o2 = x2 * t2.x + x1 * t2.y;
                    const int col = n0 + wn * 64 + nf * 16 + cc;
                    dst[(size_t)row * 1024 + col] = f2bf(o1);
                    dst[(size_t)row * 1024 + col + 32] = f2bf(o2);
                }
            }
    } else {
        // V: store transposed into vt[bh*64+d][pos], pos = within-64-tile key permutation:
        // key bits (wm, mf, gg1, gg0, reg1, reg0) -> pos = wm*32 + gg1*16 + gg0*8 + mf*4 + reg
        const int bb = m0 >> 11;                 // batch
        const int gg = lane >> 4;
        const int tb = m0 & (N_ - 1);            // 64-aligned tile base
        #pragma unroll
        for (int mf = 0; mf < 2; ++mf) {
            const int npos = tb + wm * 32 + (gg >> 1) * 16 + (gg & 1) * 8 + mf * 4;
            #pragma unroll
            for (int nf = 0; nf < 4; ++nf) {
                const int cv = n0 - 1024 + wn * 64 + nf * 16 + cc;   // 0..1023
                const int h = cv >> 6, d = cv & 63;
                uint2 u;
                u.x = cvt_pk_bf16(acc[mf][nf][0], acc[mf][nf][1]);
                u.y = cvt_pk_bf16(acc[mf][nf][2], acc[mf][nf][3]);
                *reinterpret_cast<uint2*>(vt + ((size_t)(bb * 16 + h) * 64 + d) * 2048 + npos) = u;
            }
        }
    }
}

// ---------------- output GEMM: C = att @ Wot^T + bo (f32 out), BN=64, XCD-affine, dbuf ----------------
__global__ __launch_bounds__(256) void gemm_o_kernel(const unsigned short* __restrict__ A,
                                                     const unsigned short* __restrict__ Bt,
                                                     const float* __restrict__ bias,
                                                     float* __restrict__ Cout) {
    __shared__ unsigned short As[2][128 * 64];
    __shared__ unsigned short Bs[2][64 * 64];
    const int bid = blockIdx.x;
    const int xcd = bid & 7;
    const int ii = bid >> 3;
    const int n0 = (xcd * 2 + (ii & 1)) * 64;
    const int m0 = (ii >> 1) * 128;
    const int tid = threadIdx.x, lane = tid & 63, w = tid >> 6;
    const int wm = w >> 1, wn = w & 1;
    const int cc = lane & 15;
    const int sr = tid >> 3;
    const int sc = (tid & 7) * 8;

    f32x4 acc[4][2] = {};

    #pragma unroll
    for (int i = 0; i < 4; ++i) {
        const int r = i * 32 + sr;
        const int cs = sc ^ ((r & 7) << 3);
        gload_lds16(A + (size_t)(m0 + r) * 1024 + cs, (char*)As[0] + i * 4096 + w * 1024);
        if (i < 2)
            gload_lds16(Bt + (size_t)(n0 + r) * 1024 + cs, (char*)Bs[0] + i * 4096 + w * 1024);
    }

    for (int t = 0; t < 16; ++t) {
        if (t + 1 < 16) {
            const int k0 = (t + 1) * 64;
            char* ad = (char*)As[(t + 1) & 1];
            char* bd = (char*)Bs[(t + 1) & 1];
            #pragma unroll
            for (int i = 0; i < 4; ++i) {
                const int r = i * 32 + sr;
                const int cs = sc ^ ((r & 7) << 3);
                gload_lds16(A + (size_t)(m0 + r) * 1024 + k0 + cs, ad + i * 4096 + w * 1024);
                if (i < 2)
                    gload_lds16(Bt + (size_t)(n0 + r) * 1024 + k0 + cs, bd + i * 4096 + w * 1024);
            }
            asm volatile("s_waitcnt vmcnt(6)" ::: "memory");
        } else {
            asm volatile("s_waitcnt vmcnt(0)" ::: "memory");
        }
        __builtin_amdgcn_s_barrier();

        const char* Ac = (const char*)As[t & 1];
        const char* Bc = (const char*)Bs[t & 1];

        short8 af[4][2], bf[2][2];
        #pragma unroll
        for (int mf = 0; mf < 4; ++mf)
            #pragma unroll
            for (int ks = 0; ks < 2; ++ks) {
                const int r = wm * 64 + mf * 16 + cc;
                const int cb = (ks * 64 + ((lane >> 4) * 16)) ^ ((r & 7) << 4);
                af[mf][ks] = *reinterpret_cast<const short8*>(Ac + r * 128 + cb);
            }
        #pragma unroll
        for (int nf = 0; nf < 2; ++nf)
            #pragma unroll
            for (int ks = 0; ks < 2; ++ks) {
                const int r = wn * 32 + nf * 16 + cc;
                const int cb = (ks * 64 + ((lane >> 4) * 16)) ^ ((r & 7) << 4);
                bf[nf][ks] = *reinterpret_cast<const short8*>(Bc + r * 128 + cb);
            }
        #pragma unroll
        for (int ks = 0; ks < 2; ++ks)
            #pragma unroll
            for (int mf = 0; mf < 4; ++mf)
                #pragma unroll
                for (int nf = 0; nf < 2; ++nf)
                    acc[mf][nf] = __builtin_amdgcn_mfma_f32_16x16x32_bf16(af[mf][ks], bf[nf][ks], acc[mf][nf], 0, 0, 0);

        __builtin_amdgcn_s_barrier();
    }

    float bb[2];
    #pragma unroll
    for (int nf = 0; nf < 2; ++nf) bb[nf] = bias[n0 + wn * 32 + nf * 16 + cc];
    #pragma unroll
    for (int mf = 0; mf < 4; ++mf)
        #pragma unroll
        for (int nf = 0; nf < 2; ++nf)
            #pragma unroll
            for (int reg = 0; reg < 4; ++reg) {
                const int row = m0 + wm * 64 + mf * 16 + (lane >> 4) * 4 + reg;
                const int col = n0 + wn * 32 + nf * 16 + cc;
                Cout[(size_t)row * 1024 + col] = acc[mf][nf][reg] + bb[nf];
            }
}

// ---------------- bf16 MFMA causal flash attention, split-KV, 24KB LDS, P fully in-register ----
// grid 1536. xcd=bid&7 (bh affinity). s<16: unsplit qi=s; s>=16: split halves -> pO/pml + merge.
// PV B-operand (P) built IN REGISTERS: pf[ks] = (st[2ks][0..3], st[2ks+1][0..3]) packed bf16.
// Correct because vt stores keys at bit-permuted positions (see gemm_qkv V epilogue):
// vf k-slot j2 holds key (2ks + (j2>>2))*16 + 4g + (j2&3) — exactly pf's element key.
__global__ __launch_bounds__(256, 6) void attn_mfma_kernel(const unsigned short* __restrict__ q,
                                                           const unsigned short* __restrict__ kb,
                                                           const unsigned short* __restrict__ vt,
                                                           unsigned short* __restrict__ att,
                                                           unsigned short* __restrict__ pO,
                                                           float2* __restrict__ pml) {
    const int bid = blockIdx.x;
    const int xcd = bid & 7;
    const int rest = bid >> 3;          // 0..191
    const int bh = xcd * 4 + rest / 48;
    const int s = 47 - (rest % 48);
    int qi, t0, t1, half;
    bool split;
    if (s < 16) {
        qi = s; t0 = 0; t1 = qi + 1; half = 0; split = false;
    } else {
        const int qs = s - 16;
        qi = 16 + (qs >> 1);
        half = qs & 1;
        const int hmid = (qi + 2) >> 1;
        t0 = half ? hmid : 0;
        t1 = half ? (qi + 1) : hmid;
        split = true;
    }
    const int b = bh >> 4, h = bh & 15;
    const int qb_ = qi * 64;
    const int tid = threadIdx.x;
    const int lane = tid & 63;
    const int w = tid >> 6;
    const int c = lane & 15;
    const int g = lane >> 4;

    __shared__ __align__(16) unsigned short Ks[2][64 * 64];   // [key][d] swizzled (dbuf, 16KB)
    __shared__ __align__(16) unsigned short Vs[64 * 64];      // [d][key-pos] swizzled (8KB)

    const int qrow = qb_ + w * 16 + c;
    short8 qf[2];
    {
        const unsigned short* qp = q + (size_t)(b * N_ + qrow) * 1024 + h * 64 + g * 8;
        qf[0] = *reinterpret_cast<const short8*>(qp);
        qf[1] = *reinterpret_cast<const short8*>(qp + 32);
    }

    float m = -1e30f, l = 0.f;
    f32x4 oacc[4] = {};

    const int sr = tid >> 3, sc = (tid & 7) * 8;
    const unsigned short* kbase = kb + (size_t)b * N_ * 1024 + h * 64;
    const unsigned short* vbase = vt + (size_t)bh * 64 * 2048;

    // prologue: stage K[t0] into buf (t0&1), V[t0] into the single V buffer
    #pragma unroll
    for (int i = 0; i < 2; ++i) {
        const int r = i * 32 + sr;
        const int cs = sc ^ ((r & 7) << 3);
        gload_lds16(kbase + (size_t)(t0 * 64 + r) * 1024 + cs,
                    (char*)Ks[t0 & 1] + i * 4096 + w * 1024);
        gload_lds16(vbase + (size_t)r * 2048 + t0 * 64 + cs,
                    (char*)Vs + i * 4096 + w * 1024);
    }

    for (int t = t0; t < t1; ++t) {
        const int jb = t * 64;
        const int jn = jb + 64;
        if (t + 1 < t1) {
            char* kd = (char*)Ks[(t + 1) & 1];
            #pragma unroll
            for (int i = 0; i < 2; ++i) {
                const int r = i * 32 + sr;
                const int cs = sc ^ ((r & 7) << 3);
                gload_lds16(kbase + (size_t)(jn + r) * 1024 + cs, kd + i * 4096 + w * 1024);
            }
            asm volatile("s_waitcnt vmcnt(2)" ::: "memory");  // K[t],V[t] landed; K[t+1] flying
        } else {
            asm volatile("s_waitcnt vmcnt(0)" ::: "memory");
        }
        __builtin_amdgcn_s_barrier();

        const char* Ksc = (const char*)Ks[t & 1];
        const char* Vsc = (const char*)Vs;

        f32x4 st[4];
        __builtin_amdgcn_s_setprio(1);
        #pragma unroll
        for (int ct = 0; ct < 4; ++ct) {
            const int key = ct * 16 + c;
            f32x4 acc = {0.f, 0.f, 0.f, 0.f};
            #pragma unroll
            for (int ks = 0; ks < 2; ++ks) {
                const int addr = (key * 128 + ks * 64 + g * 16) ^ ((key & 7) << 4);
                const short8 kf = *reinterpret_cast<const short8*>(Ksc + addr);
                acc = __builtin_amdgcn_mfma_f32_16x16x32_bf16(kf, qf[ks], acc, 0, 0, 0);
            }
            st[ct] = acc;
        }
        __builtin_amdgcn_s_setprio(0);

        // exp2-domain online softmax with defer-max (lane owns row qrow; key = jb+ct*16+g*4+reg)
        float mx = -1e30f;
        if (jb + 63 > qrow) {
            #pragma unroll
            for (int ct = 0; ct < 4; ++ct)
                #pragma unroll
                for (int reg = 0; reg < 4; ++reg) {
                    const int key = jb + ct * 16 + g * 4 + reg;
                    const float sv = (key <= qrow) ? st[ct][reg] : -1e30f;
                    st[ct][reg] = sv;
                    mx = fmaxf(mx, sv);
                }
        } else {
            #pragma unroll
            for (int ct = 0; ct < 4; ++ct)
                mx = fmaxf(mx, fmaxf(fmaxf(st[ct][0], st[ct][1]),
                                     fmaxf(st[ct][2], st[ct][3])));
        }
        mx = fmaxf(mx, __shfl_xor(mx, 16, 64));
        mx = fmaxf(mx, __shfl_xor(mx, 32, 64));
        if (!__all(mx <= m + 8.0f)) {
            const float mn = fmaxf(m, mx);
            const float corr = exp2_fast(m - mn);
            l *= corr;
            m = mn;
            #pragma unroll
            for (int dt = 0; dt < 4; ++dt) {
                oacc[dt][0] *= corr; oacc[dt][1] *= corr;
                oacc[dt][2] *= corr; oacc[dt][3] *= corr;
            }
        }
        float rs = 0.f;
        #pragma unroll
        for (int ct = 0; ct < 4; ++ct)
            #pragma unroll
            for (int reg = 0; reg < 4; ++reg) {
                const float p = exp2_fast(st[ct][reg] - m);
                st[ct][reg] = p;
                rs += p;
            }
        rs += __shfl_xor(rs, 16, 64);
        rs += __shfl_xor(rs, 32, 64);
        l += rs;

        // P -> bf16 fully in-register (no LDS round trip)
        uint4v pv0, pv1;
        pv0[0] = cvt_pk_bf16(st[0][0], st[0][1]);
        pv0[1] = cvt_pk_bf16(st[0][2], st[0][3]);
        pv0[2] = cvt_pk_bf16(st[1][0], st[1][1]);
        pv0[3] = cvt_pk_bf16(st[1][2], st[1][3]);
        pv1[0] = cvt_pk_bf16(st[2][0], st[2][1]);
        pv1[1] = cvt_pk_bf16(st[2][2], st[2][3]);
        pv1[2] = cvt_pk_bf16(st[3][0], st[3][1]);
        pv1[3] = cvt_pk_bf16(st[3][2], st[3][3]);
        const short8 pf0 = *reinterpret_cast<const short8*>(&pv0);
        const short8 pf1 = *reinterpret_cast<const short8*>(&pv1);

        // O^T += V^T · P^T  (vf positions hold permuted keys matching pf's element keys)
        __builtin_amdgcn_s_setprio(1);
        #pragma unroll
        for (int dt = 0; dt < 4; ++dt) {
            const int vd = dt * 16 + c;
            {
                const int addr = (vd * 128 + 0 * 64 + g * 16) ^ ((vd & 7) << 4);
                const short8 vf = *reinterpret_cast<const short8*>(Vsc + addr);
                oacc[dt] = __builtin_amdgcn_mfma_f32_16x16x32_bf16(vf, pf0, oacc[dt], 0, 0, 0);
            }
            {
                const int addr = (vd * 128 + 1 * 64 + g * 16) ^ ((vd & 7) << 4);
                const short8 vf = *reinterpret_cast<const short8*>(Vsc + addr);
                oacc[dt] = __builtin_amdgcn_mfma_f32_16x16x32_bf16(vf, pf1, oacc[dt], 0, 0, 0);
            }
        }
        __builtin_amdgcn_s_setprio(0);

        __builtin_amdgcn_s_barrier();   // all waves done reading Vs / Ks[t&1]

        if (t + 1 < t1) {   // stage V[t+1] into the single V buffer
            #pragma unroll
            for (int i = 0; i < 2; ++i) {
                const int r = i * 32 + sr;
                const int cs = sc ^ ((r & 7) << 3);
                gload_lds16(vbase + (size_t)r * 2048 + jn + cs, (char*)Vs + i * 4096 + w * 1024);
            }
        }
    }

    if (!split) {
        const float inv = 1.0f / l;
        unsigned short* orow = att + (size_t)(b * N_ + qrow) * 1024 + h * 64;
        #pragma unroll
        for (int dt = 0; dt < 4; ++dt) {
            #pragma unroll
            for (int rp = 0; rp < 2; ++rp) {
                const unsigned u = cvt_pk_bf16(oacc[dt][2 * rp] * inv,
                                               oacc[dt][2 * rp + 1] * inv);
                *reinterpret_cast<unsigned*>(orow + dt * 16 + g * 4 + rp * 2) = u;
            }
        }
    } else {
        const int slot = (bh * 16 + (qi - 16)) * 2 + half;
        const int rloc = w * 16 + c;
        pml[slot * 64 + rloc] = make_float2(m, l);
        unsigned short* prow = pO + (size_t)slot * 4096 + rloc * 64;
        #pragma unroll
        for (int dt = 0; dt < 4; ++dt) {
            #pragma unroll
            for (int rp = 0; rp < 2; ++rp) {
                const unsigned u = cvt_pk_bf16(oacc[dt][2 * rp], oacc[dt][2 * rp + 1]);
                *reinterpret_cast<unsigned*>(prow + dt * 16 + g * 4 + rp * 2) = u;
            }
        }
    }
}

// ---------------- merge split-KV partials ----------------
__global__ __launch_bounds__(256) void attn_merge_kernel(const unsigned short* __restrict__ pO,
                                                         const float2* __restrict__ pml,
                                                         unsigned short* __restrict__ att) {
    const int blk = blockIdx.x;        // 0..511 = bh*16 + qt
    const int bh = blk >> 4;
    const int qt = blk & 15;
    const int qi = 16 + qt;
    const int b = bh >> 4, h = bh & 15;
    const int tid = threadIdx.x;
    const int row = tid >> 2;
    const int d0 = (tid & 3) * 16;
    const int slot0 = (bh * 16 + qt) * 2;
    const float2 ml0 = pml[slot0 * 64 + row];
    const float2 ml1 = pml[(slot0 + 1) * 64 + row];
    const float M = fmaxf(ml0.x, ml1.x);
    const float w0 = exp2_fast(ml0.x - M);
    const float w1 = exp2_fast(ml1.x - M);
    const float invL = 1.0f / (ml0.y * w0 + ml1.y * w1);
    const unsigned short* p0 = pO + (size_t)slot0 * 4096 + row * 64 + d0;
    const unsigned short* p1 = p0 + 4096;
    const int qrow = qi * 64 + row;
    unsigned short* orow = att + (size_t)(b * N_ + qrow) * 1024 + h * 64 + d0;
    #pragma unroll
    for (int j = 0; j < 16; j += 2) {
        const float a0 = (bf2f(p0[j]) * w0 + bf2f(p1[j]) * w1) * invL;
        const float a1 = (bf2f(p0[j + 1]) * w0 + bf2f(p1[j + 1]) * w1) * invL;
        *reinterpret_cast<unsigned*>(orow + j) = cvt_pk_bf16(a0, a1);
    }
}

extern "C" void kernel_launch(void* const* d_in, const int* in_sizes, int n_in,
                              void* d_out, int out_size, void* d_ws, size_t ws_size,
                              hipStream_t stream) {
    const float* x     = (const float*)d_in[0];
    const float* pos   = (const float*)d_in[1];
    const float* gamma = (const float*)d_in[2];
    const float* Wq    = (const float*)d_in[3];
    const float* Wkv   = (const float*)d_in[4];
    const float* Wo    = (const float*)d_in[5];
    const float* bo    = (const float*)d_in[6];
    float* out = (float*)d_out;
    char* ws = (char*)d_ws;

    const size_t MB = 1024 * 1024;
    unsigned short* kb   = (unsigned short*)(ws);             // 8 MB roped K
    unsigned short* qb   = (unsigned short*)(ws + 16 * MB);   // 8 MB roped+scaled Q
    unsigned short* att  = (unsigned short*)(ws + 24 * MB);   // 8 MB attention output
    unsigned short* xb   = (unsigned short*)(ws + 32 * MB);   // 8 MB bf16 x (dead after qkv)
    unsigned short* Wqt  = (unsigned short*)(ws + 40 * MB);   // 2 MB
    unsigned short* Wkvt = (unsigned short*)(ws + 42 * MB);   // 4 MB
    unsigned short* Wot  = (unsigned short*)(ws + 46 * MB);   // 2 MB
    unsigned short* vt   = (unsigned short*)(ws + 48 * MB);   // 8 MB V^T [bh][d][pos]
    float2* tabq         = (float2*)(ws + 56 * MB);           // 1 MB
    float2* tabk         = (float2*)(ws + 57 * MB);           // 1 MB
    float* sv            = (float*)(ws + 58 * MB);            // 16 KB
    unsigned short* pO   = (unsigned short*)(ws + 32 * MB);   // 8.4 MB (overlay)
    float2* pml          = (float2*)(ws + 40 * MB + 512 * 1024);  // 512 KB

    freqtab_kernel<<<512, 256, 0, stream>>>(pos, tabq, tabk);
    convT_all_kernel<<<dim3(128, 32), 256, 0, stream>>>(Wq, Wkv, Wo, gamma, Wqt, Wkvt, Wot);
    rmsnorm_kernel<<<B_ * N_, 256, 0, stream>>>(x, xb, sv);

    gemm_qkv_kernel<<<1536, 256, 0, stream>>>(
        xb, Wqt, Wkvt, sv, qb, kb, vt, tabq, tabk);

    attn_mfma_kernel<<<1536, 256, 0, stream>>>(qb, kb, vt, att, pO, pml);
    attn_merge_kernel<<<512, 256, 0, stream>>>(pO, pml, att);

    gemm_o_kernel<<<512, 256, 0, stream>>>(att, Wot, bo, out);
}

// Round 19
// 113.523 us; speedup vs baseline: 1.0770x; 1.0408x over previous
//
#include <hip/hip_runtime.h>
#include <cmath>

#define B_ 2
#define N_ 2048
#define D_ 1024
#define H_ 16

typedef __attribute__((ext_vector_type(8))) short short8;
typedef __attribute__((ext_vector_type(4))) float f32x4;
typedef __attribute__((ext_vector_type(4))) unsigned short u16x4;
typedef __attribute__((ext_vector_type(4))) unsigned int uint4v;

__device__ __forceinline__ unsigned short f2bf(float f) {
    union { float f; unsigned u; } x;
    x.f = f;
    unsigned r = x.u + 0x7FFFu + ((x.u >> 16) & 1u);
    return (unsigned short)(r >> 16);
}
__device__ __forceinline__ float bf2f(unsigned short u) {
    union { unsigned u; float f; } x;
    x.u = ((unsigned)u) << 16;
    return x.f;
}
__device__ __forceinline__ unsigned cvt_pk_bf16(float lo, float hi) {
    unsigned r;
    asm("v_cvt_pk_bf16_f32 %0, %1, %2" : "=v"(r) : "v"(lo), "v"(hi));
    return r;
}
__device__ __forceinline__ float exp2_fast(float x) {
    float r;
    asm("v_exp_f32 %0, %1" : "=v"(r) : "v"(x));
    return r;
}
__device__ __forceinline__ void gload_lds16(const void* g, void* l) {
    __builtin_amdgcn_global_load_lds((const __attribute__((address_space(1))) unsigned*)g,
                                     (__attribute__((address_space(3))) unsigned*)l,
                                     16, 0, 0);
}

// ---------------- cos/sin tables (trig once; q table pre-scaled by 0.125*log2e) ----------------
__global__ __launch_bounds__(256) void freqtab_kernel(const float* __restrict__ pos,
                                                      float2* __restrict__ tabq,
                                                      float2* __restrict__ tabk) {
    const int idx = blockIdx.x * 256 + threadIdx.x;   // N_*64 = 131072
    const float f = pos[idx];
    const float cc = cosf(f), ss = sinf(f);
    const float sq = 0.125f * 1.4426950408889634f;    // DH^-0.5 * log2(e)
    tabq[idx] = make_float2(sq * cc, sq * ss);
    tabk[idx] = make_float2(cc, ss);
}

// ---------------- RMS-like norm: emit bf16 x copy + per-row scale s ----------------
__global__ __launch_bounds__(256) void rmsnorm_kernel(const float* __restrict__ x,
                                                      unsigned short* __restrict__ xb,
                                                      float* __restrict__ s) {
    const int row = blockIdx.x;
    const float4 v = reinterpret_cast<const float4*>(x + (size_t)row * D_)[threadIdx.x];
    float ss = v.x * v.x + v.y * v.y + v.z * v.z + v.w * v.w;
    #pragma unroll
    for (int off = 32; off; off >>= 1) ss += __shfl_xor(ss, off, 64);
    __shared__ float wss[4];
    if ((threadIdx.x & 63) == 0) wss[threadIdx.x >> 6] = ss;
    __syncthreads();
    const float tot = wss[0] + wss[1] + wss[2] + wss[3];
    const float inv = 1.0f / fmaxf(sqrtf(tot * (1.0f / D_)), 1e-8f);
    if (threadIdx.x == 0) s[row] = inv;
    u16x4 ox;
    ox[0] = f2bf(v.x); ox[1] = f2bf(v.y); ox[2] = f2bf(v.z); ox[3] = f2bf(v.w);
    *reinterpret_cast<u16x4*>(xb + (size_t)row * D_ + threadIdx.x * 4) = ox;
}

// ---------------- all 3 weight transposes (gamma folded into Wq) ----------------
__global__ __launch_bounds__(256) void convT_all_kernel(const float* __restrict__ Wq,
                                                        const float* __restrict__ Wkv,
                                                        const float* __restrict__ Wo,
                                                        const float* __restrict__ gamma,
                                                        unsigned short* __restrict__ Wqt,
                                                        unsigned short* __restrict__ Wkvt,
                                                        unsigned short* __restrict__ Wot) {
    __shared__ float tile[32][33];
    const int bx = blockIdx.x;   // 0..127 over concat {Wq:32, Wkv:64, Wo:32}
    const float* W;
    unsigned short* Wt;
    int Nm, n0;
    bool gmul = false;
    if (bx < 32)       { W = Wq;  Wt = Wqt;  Nm = 1024; n0 = bx * 32; gmul = true; }
    else if (bx < 96)  { W = Wkv; Wt = Wkvt; Nm = 2048; n0 = (bx - 32) * 32; }
    else               { W = Wo;  Wt = Wot;  Nm = 1024; n0 = (bx - 96) * 32; }
    const int k0 = blockIdx.y * 32;
    const int r = threadIdx.x >> 3, c4 = (threadIdx.x & 7) * 4;
    const float4 ld = *reinterpret_cast<const float4*>(W + (size_t)(k0 + r) * Nm + n0 + c4);
    tile[r][c4 + 0] = ld.x; tile[r][c4 + 1] = ld.y;
    tile[r][c4 + 2] = ld.z; tile[r][c4 + 3] = ld.w;
    __syncthreads();
    u16x4 o;
    #pragma unroll
    for (int j = 0; j < 4; ++j) {
        float v = tile[c4 + j][r];
        if (gmul) v *= gamma[k0 + c4 + j];
        o[j] = f2bf(v);
    }
    *reinterpret_cast<u16x4*>(Wt + (size_t)(n0 + r) * 1024 + k0 + c4) = o;
}

// ---------------- merged q + kv GEMM: BM=64, BN=128, BK=64, dbuf, vmcnt(6) ----------------
// grid 1536 = 8 XCD x 3 panels x 64 m-tiles. xcd=bid&7 owns bx in [3*xcd, 3*xcd+3).
// bx 0-7: q -> qb (rope tabq, s-scaled); 8-15: K -> kb (rope tabk);
// 16-23: V -> vt with within-64-tile KEY PERMUTATION p: p4=k3,p3=k2,p2=k4 (low 2 bits kept)
// so attention's PV B-operand is lane-local (see attn kernel).
__global__ __launch_bounds__(256) void gemm_qkv_kernel(const unsigned short* __restrict__ xb,
                                                       const unsigned short* __restrict__ Wqt,
                                                       const unsigned short* __restrict__ Wkvt,
                                                       const float* __restrict__ s,
                                                       unsigned short* __restrict__ qb,
                                                       unsigned short* __restrict__ kb,
                                                       unsigned short* __restrict__ vt,
                                                       const float2* __restrict__ tabq,
                                                       const float2* __restrict__ tabk) {
    __shared__ unsigned short As[2][64 * 64];    // 8KB each
    __shared__ unsigned short Bs[2][128 * 64];   // 16KB each
    __shared__ float sld[64];
    const int bid = blockIdx.x;
    const int xcd = bid & 7;
    const int ii = bid >> 3;                 // 0..191
    const int bx = xcd * 3 + (ii % 3);       // 0..23
    const int m0 = (ii / 3) * 64;            // 0..4032

    const unsigned short* Bt;
    int n0;
    if (bx < 8)       { Bt = Wqt;  n0 = bx * 128; }
    else if (bx < 16) { Bt = Wkvt; n0 = (bx - 8) * 128; }
    else              { Bt = Wkvt; n0 = (bx - 16) * 128 + 1024; }

    const int tid = threadIdx.x, lane = tid & 63, w = tid >> 6;
    const int wm = w >> 1, wn = w & 1;       // wave tile 32 x 64
    const int cc = lane & 15;
    const int sr = tid >> 3;                 // 0..31
    const int sc = (tid & 7) * 8;

    if (tid < 64) sld[tid] = s[m0 + tid];

    f32x4 acc[2][4] = {};

    // prologue: stage K-step 0 into buf 0 (A: 2 units of 32 rows; B: 4 units)
    #pragma unroll
    for (int i = 0; i < 4; ++i) {
        const int r = i * 32 + sr;
        const int cs = sc ^ ((r & 7) << 3);
        if (i < 2)
            gload_lds16(xb + (size_t)(m0 + r) * 1024 + cs, (char*)As[0] + i * 4096 + w * 1024);
        gload_lds16(Bt + (size_t)(n0 + r) * 1024 + cs, (char*)Bs[0] + i * 4096 + w * 1024);
    }

    for (int t = 0; t < 16; ++t) {
        if (t + 1 < 16) {
            const int k0 = (t + 1) * 64;
            char* ad = (char*)As[(t + 1) & 1];
            char* bd = (char*)Bs[(t + 1) & 1];
            #pragma unroll
            for (int i = 0; i < 4; ++i) {
                const int r = i * 32 + sr;
                const int cs = sc ^ ((r & 7) << 3);
                if (i < 2)
                    gload_lds16(xb + (size_t)(m0 + r) * 1024 + k0 + cs, ad + i * 4096 + w * 1024);
                gload_lds16(Bt + (size_t)(n0 + r) * 1024 + k0 + cs, bd + i * 4096 + w * 1024);
            }
            asm volatile("s_waitcnt vmcnt(6)" ::: "memory");  // this step landed; next 6 flying
        } else {
            asm volatile("s_waitcnt vmcnt(0)" ::: "memory");
        }
        __builtin_amdgcn_s_barrier();

        const char* Ac = (const char*)As[t & 1];
        const char* Bc = (const char*)Bs[t & 1];

        short8 af[2][2], bf[4][2];
        #pragma unroll
        for (int mf = 0; mf < 2; ++mf)
            #pragma unroll
            for (int ks = 0; ks < 2; ++ks) {
                const int r = wm * 32 + mf * 16 + cc;
                const int cb = (ks * 64 + ((lane >> 4) * 16)) ^ ((r & 7) << 4);
                af[mf][ks] = *reinterpret_cast<const short8*>(Ac + r * 128 + cb);
            }
        #pragma unroll
        for (int nf = 0; nf < 4; ++nf)
            #pragma unroll
            for (int ks = 0; ks < 2; ++ks) {
                const int r = wn * 64 + nf * 16 + cc;
                const int cb = (ks * 64 + ((lane >> 4) * 16)) ^ ((r & 7) << 4);
                bf[nf][ks] = *reinterpret_cast<const short8*>(Bc + r * 128 + cb);
            }
        #pragma unroll
        for (int ks = 0; ks < 2; ++ks)
            #pragma unroll
            for (int mf = 0; mf < 2; ++mf)
                #pragma unroll
                for (int nf = 0; nf < 4; ++nf)
                    acc[mf][nf] = __builtin_amdgcn_mfma_f32_16x16x32_bf16(af[mf][ks], bf[nf][ks], acc[mf][nf], 0, 0, 0);

        __builtin_amdgcn_s_barrier();   // all waves done with buf[t&1] before overwrite
    }

    if (bx < 16) {
        // rope epilogue; q additionally scaled by per-row s (f32). Head = 64-col span (wn half).
        const float2* tab = (bx < 8) ? tabq : tabk;
        unsigned short* dst = (bx < 8) ? qb : kb;
        const bool doscale = (bx < 8);
        #pragma unroll
        for (int mf = 0; mf < 2; ++mf)
            #pragma unroll
            for (int reg = 0; reg < 4; ++reg) {
                const int rloc = wm * 32 + mf * 16 + (lane >> 4) * 4 + reg;
                const int row = m0 + rloc;
                const int n = row & (N_ - 1);
                const float srow = doscale ? sld[rloc] : 1.0f;
                #pragma unroll
                for (int nf = 0; nf < 2; ++nf) {
                    const int d = nf * 16 + cc;
                    const float2 t1 = tab[n * 64 + d];
                    const float2 t2 = tab[n * 64 + 32 + d];
                    const float x1 = acc[mf][nf][reg] * srow;
                    const float x2 = acc[mf][nf + 2][reg] * srow;
                    const float o1 = x1 * t1.x - x2 * t1.y;
                    const float o2 = x2 * t2.x + x1 * t2.y;
                    const int col = n0 + wn * 64 + nf * 16 + cc;
                    dst[(size_t)row * 1024 + col] = f2bf(o1);
                    dst[(size_t)row * 1024 + col + 32] = f2bf(o2);
                }
            }
    } else {
        // V: store transposed into vt[bh*64+d][pos], pos = within-64-tile key permutation:
        // key bits (wm, mf, gg1, gg0, reg1, reg0) -> pos = wm*32 + gg1*16 + gg0*8 + mf*4 + reg
        const int bb = m0 >> 11;                 // batch
        const int gg = lane >> 4;
        const int tb = m0 & (N_ - 1);            // 64-aligned tile base
        #pragma unroll
        for (int mf = 0; mf < 2; ++mf) {
            const int npos = tb + wm * 32 + (gg >> 1) * 16 + (gg & 1) * 8 + mf * 4;
            #pragma unroll
            for (int nf = 0; nf < 4; ++nf) {
                const int cv = n0 - 1024 + wn * 64 + nf * 16 + cc;   // 0..1023
                const int h = cv >> 6, d = cv & 63;
                uint2 u;
                u.x = cvt_pk_bf16(acc[mf][nf][0], acc[mf][nf][1]);
                u.y = cvt_pk_bf16(acc[mf][nf][2], acc[mf][nf][3]);
                *reinterpret_cast<uint2*>(vt + ((size_t)(bb * 16 + h) * 64 + d) * 2048 + npos) = u;
            }
        }
    }
}

// ---------------- output GEMM: C = att @ Wot^T + bo (f32 out), BN=64, XCD-affine, dbuf ----------------
__global__ __launch_bounds__(256) void gemm_o_kernel(const unsigned short* __restrict__ A,
                                                     const unsigned short* __restrict__ Bt,
                                                     const float* __restrict__ bias,
                                                     float* __restrict__ Cout) {
    __shared__ unsigned short As[2][128 * 64];
    __shared__ unsigned short Bs[2][64 * 64];
    const int bid = blockIdx.x;
    const int xcd = bid & 7;
    const int ii = bid >> 3;
    const int n0 = (xcd * 2 + (ii & 1)) * 64;
    const int m0 = (ii >> 1) * 128;
    const int tid = threadIdx.x, lane = tid & 63, w = tid >> 6;
    const int wm = w >> 1, wn = w & 1;
    const int cc = lane & 15;
    const int sr = tid >> 3;
    const int sc = (tid & 7) * 8;

    f32x4 acc[4][2] = {};

    #pragma unroll
    for (int i = 0; i < 4; ++i) {
        const int r = i * 32 + sr;
        const int cs = sc ^ ((r & 7) << 3);
        gload_lds16(A + (size_t)(m0 + r) * 1024 + cs, (char*)As[0] + i * 4096 + w * 1024);
        if (i < 2)
            gload_lds16(Bt + (size_t)(n0 + r) * 1024 + cs, (char*)Bs[0] + i * 4096 + w * 1024);
    }

    for (int t = 0; t < 16; ++t) {
        if (t + 1 < 16) {
            const int k0 = (t + 1) * 64;
            char* ad = (char*)As[(t + 1) & 1];
            char* bd = (char*)Bs[(t + 1) & 1];
            #pragma unroll
            for (int i = 0; i < 4; ++i) {
                const int r = i * 32 + sr;
                const int cs = sc ^ ((r & 7) << 3);
                gload_lds16(A + (size_t)(m0 + r) * 1024 + k0 + cs, ad + i * 4096 + w * 1024);
                if (i < 2)
                    gload_lds16(Bt + (size_t)(n0 + r) * 1024 + k0 + cs, bd + i * 4096 + w * 1024);
            }
            asm volatile("s_waitcnt vmcnt(6)" ::: "memory");
        } else {
            asm volatile("s_waitcnt vmcnt(0)" ::: "memory");
        }
        __builtin_amdgcn_s_barrier();

        const char* Ac = (const char*)As[t & 1];
        const char* Bc = (const char*)Bs[t & 1];

        short8 af[4][2], bf[2][2];
        #pragma unroll
        for (int mf = 0; mf < 4; ++mf)
            #pragma unroll
            for (int ks = 0; ks < 2; ++ks) {
                const int r = wm * 64 + mf * 16 + cc;
                const int cb = (ks * 64 + ((lane >> 4) * 16)) ^ ((r & 7) << 4);
                af[mf][ks] = *reinterpret_cast<const short8*>(Ac + r * 128 + cb);
            }
        #pragma unroll
        for (int nf = 0; nf < 2; ++nf)
            #pragma unroll
            for (int ks = 0; ks < 2; ++ks) {
                const int r = wn * 32 + nf * 16 + cc;
                const int cb = (ks * 64 + ((lane >> 4) * 16)) ^ ((r & 7) << 4);
                bf[nf][ks] = *reinterpret_cast<const short8*>(Bc + r * 128 + cb);
            }
        #pragma unroll
        for (int ks = 0; ks < 2; ++ks)
            #pragma unroll
            for (int mf = 0; mf < 4; ++mf)
                #pragma unroll
                for (int nf = 0; nf < 2; ++nf)
                    acc[mf][nf] = __builtin_amdgcn_mfma_f32_16x16x32_bf16(af[mf][ks], bf[nf][ks], acc[mf][nf], 0, 0, 0);

        __builtin_amdgcn_s_barrier();
    }

    float bb[2];
    #pragma unroll
    for (int nf = 0; nf < 2; ++nf) bb[nf] = bias[n0 + wn * 32 + nf * 16 + cc];
    #pragma unroll
    for (int mf = 0; mf < 4; ++mf)
        #pragma unroll
        for (int nf = 0; nf < 2; ++nf)
            #pragma unroll
            for (int reg = 0; reg < 4; ++reg) {
                const int row = m0 + wm * 64 + mf * 16 + (lane >> 4) * 4 + reg;
                const int col = n0 + wn * 32 + nf * 16 + cc;
                Cout[(size_t)row * 1024 + col] = acc[mf][nf][reg] + bb[nf];
            }
}

// ---------------- bf16 MFMA causal flash attention, split-KV, 24KB LDS, P fully in-register ----
// grid 1536. xcd=bid&7 (bh affinity). Balanced CU mapping: co-resident blocks (same u=rest&31,
// v=0..5) get one complementary pair from each work class -> per-CU work 65-67 units (was 46-88):
//   v pair (0,1): unsplit s = p / 15-p (work sums 17)
//   v pair (2,3): split-low s = 16+p / 31-p (sums 20-21)
//   v pair (4,5): split-high s = 32+p / 47-p (sums 28-29)
// bh alternates with v parity so each (bh, s) appears exactly once.
// s<16: unsplit qi=s; s>=16: split halves -> pO/pml + merge.
__global__ __launch_bounds__(256, 6) void attn_mfma_kernel(const unsigned short* __restrict__ q,
                                                           const unsigned short* __restrict__ kb,
                                                           const unsigned short* __restrict__ vt,
                                                           unsigned short* __restrict__ att,
                                                           unsigned short* __restrict__ pO,
                                                           float2* __restrict__ pml) {
    const int bid = blockIdx.x;
    const int xcd = bid & 7;
    const int rest = bid >> 3;          // 0..191
    const int v = rest >> 5;            // 0..5
    const int u = rest & 31;            // 0..31
    const int a = u >> 4;               // 0..1
    const int p = u & 15;               // 0..15
    const int bh = xcd * 4 + 2 * a + (v & 1);
    const int s = (v >> 1) * 16 + ((v & 1) ? (15 - p) : p);
    int qi, t0, t1, half;
    bool split;
    if (s < 16) {
        qi = s; t0 = 0; t1 = qi + 1; half = 0; split = false;
    } else {
        const int qs = s - 16;
        qi = 16 + (qs >> 1);
        half = qs & 1;
        const int hmid = (qi + 2) >> 1;
        t0 = half ? hmid : 0;
        t1 = half ? (qi + 1) : hmid;
        split = true;
    }
    const int b = bh >> 4, h = bh & 15;
    const int qb_ = qi * 64;
    const int tid = threadIdx.x;
    const int lane = tid & 63;
    const int w = tid >> 6;
    const int c = lane & 15;
    const int g = lane >> 4;

    __shared__ __align__(16) unsigned short Ks[2][64 * 64];   // [key][d] swizzled (dbuf, 16KB)
    __shared__ __align__(16) unsigned short Vs[64 * 64];      // [d][key-pos] swizzled (8KB)

    const int qrow = qb_ + w * 16 + c;
    short8 qf[2];
    {
        const unsigned short* qp = q + (size_t)(b * N_ + qrow) * 1024 + h * 64 + g * 8;
        qf[0] = *reinterpret_cast<const short8*>(qp);
        qf[1] = *reinterpret_cast<const short8*>(qp + 32);
    }

    float m = -1e30f, l = 0.f;
    f32x4 oacc[4] = {};

    const int sr = tid >> 3, sc = (tid & 7) * 8;
    const unsigned short* kbase = kb + (size_t)b * N_ * 1024 + h * 64;
    const unsigned short* vbase = vt + (size_t)bh * 64 * 2048;

    // prologue: stage K[t0] into buf (t0&1), V[t0] into the single V buffer
    #pragma unroll
    for (int i = 0; i < 2; ++i) {
        const int r = i * 32 + sr;
        const int cs = sc ^ ((r & 7) << 3);
        gload_lds16(kbase + (size_t)(t0 * 64 + r) * 1024 + cs,
                    (char*)Ks[t0 & 1] + i * 4096 + w * 1024);
        gload_lds16(vbase + (size_t)r * 2048 + t0 * 64 + cs,
                    (char*)Vs + i * 4096 + w * 1024);
    }

    for (int t = t0; t < t1; ++t) {
        const int jb = t * 64;
        const int jn = jb + 64;
        if (t + 1 < t1) {
            char* kd = (char*)Ks[(t + 1) & 1];
            #pragma unroll
            for (int i = 0; i < 2; ++i) {
                const int r = i * 32 + sr;
                const int cs = sc ^ ((r & 7) << 3);
                gload_lds16(kbase + (size_t)(jn + r) * 1024 + cs, kd + i * 4096 + w * 1024);
            }
            asm volatile("s_waitcnt vmcnt(2)" ::: "memory");  // K[t],V[t] landed; K[t+1] flying
        } else {
            asm volatile("s_waitcnt vmcnt(0)" ::: "memory");
        }
        __builtin_amdgcn_s_barrier();

        const char* Ksc = (const char*)Ks[t & 1];
        const char* Vsc = (const char*)Vs;

        f32x4 st[4];
        __builtin_amdgcn_s_setprio(1);
        #pragma unroll
        for (int ct = 0; ct < 4; ++ct) {
            const int key = ct * 16 + c;
            f32x4 acc = {0.f, 0.f, 0.f, 0.f};
            #pragma unroll
            for (int ks = 0; ks < 2; ++ks) {
                const int addr = (key * 128 + ks * 64 + g * 16) ^ ((key & 7) << 4);
                const short8 kf = *reinterpret_cast<const short8*>(Ksc + addr);
                acc = __builtin_amdgcn_mfma_f32_16x16x32_bf16(kf, qf[ks], acc, 0, 0, 0);
            }
            st[ct] = acc;
        }
        __builtin_amdgcn_s_setprio(0);

        // exp2-domain online softmax with defer-max (lane owns row qrow; key = jb+ct*16+g*4+reg)
        float mx = -1e30f;
        if (jb + 63 > qrow) {
            #pragma unroll
            for (int ct = 0; ct < 4; ++ct)
                #pragma unroll
                for (int reg = 0; reg < 4; ++reg) {
                    const int key = jb + ct * 16 + g * 4 + reg;
                    const float sv = (key <= qrow) ? st[ct][reg] : -1e30f;
                    st[ct][reg] = sv;
                    mx = fmaxf(mx, sv);
                }
        } else {
            #pragma unroll
            for (int ct = 0; ct < 4; ++ct)
                mx = fmaxf(mx, fmaxf(fmaxf(st[ct][0], st[ct][1]),
                                     fmaxf(st[ct][2], st[ct][3])));
        }
        mx = fmaxf(mx, __shfl_xor(mx, 16, 64));
        mx = fmaxf(mx, __shfl_xor(mx, 32, 64));
        if (!__all(mx <= m + 8.0f)) {
            const float mn = fmaxf(m, mx);
            const float corr = exp2_fast(m - mn);
            l *= corr;
            m = mn;
            #pragma unroll
            for (int dt = 0; dt < 4; ++dt) {
                oacc[dt][0] *= corr; oacc[dt][1] *= corr;
                oacc[dt][2] *= corr; oacc[dt][3] *= corr;
            }
        }
        float rs = 0.f;
        #pragma unroll
        for (int ct = 0; ct < 4; ++ct)
            #pragma unroll
            for (int reg = 0; reg < 4; ++reg) {
                const float p2 = exp2_fast(st[ct][reg] - m);
                st[ct][reg] = p2;
                rs += p2;
            }
        rs += __shfl_xor(rs, 16, 64);
        rs += __shfl_xor(rs, 32, 64);
        l += rs;

        // P -> bf16 fully in-register (no LDS round trip)
        uint4v pv0, pv1;
        pv0[0] = cvt_pk_bf16(st[0][0], st[0][1]);
        pv0[1] = cvt_pk_bf16(st[0][2], st[0][3]);
        pv0[2] = cvt_pk_bf16(st[1][0], st[1][1]);
        pv0[3] = cvt_pk_bf16(st[1][2], st[1][3]);
        pv1[0] = cvt_pk_bf16(st[2][0], st[2][1]);
        pv1[1] = cvt_pk_bf16(st[2][2], st[2][3]);
        pv1[2] = cvt_pk_bf16(st[3][0], st[3][1]);
        pv1[3] = cvt_pk_bf16(st[3][2], st[3][3]);
        const short8 pf0 = *reinterpret_cast<const short8*>(&pv0);
        const short8 pf1 = *reinterpret_cast<const short8*>(&pv1);

        // O^T += V^T · P^T  (vf positions hold permuted keys matching pf's element keys)
        __builtin_amdgcn_s_setprio(1);
        #pragma unroll
        for (int dt = 0; dt < 4; ++dt) {
            const int vd = dt * 16 + c;
            {
                const int addr = (vd * 128 + 0 * 64 + g * 16) ^ ((vd & 7) << 4);
                const short8 vf = *reinterpret_cast<const short8*>(Vsc + addr);
                oacc[dt] = __builtin_amdgcn_mfma_f32_16x16x32_bf16(vf, pf0, oacc[dt], 0, 0, 0);
            }
            {
                const int addr = (vd * 128 + 1 * 64 + g * 16) ^ ((vd & 7) << 4);
                const short8 vf = *reinterpret_cast<const short8*>(Vsc + addr);
                oacc[dt] = __builtin_amdgcn_mfma_f32_16x16x32_bf16(vf, pf1, oacc[dt], 0, 0, 0);
            }
        }
        __builtin_amdgcn_s_setprio(0);

        __builtin_amdgcn_s_barrier();   // all waves done reading Vs / Ks[t&1]

        if (t + 1 < t1) {   // stage V[t+1] into the single V buffer
            #pragma unroll
            for (int i = 0; i < 2; ++i) {
                const int r = i * 32 + sr;
                const int cs = sc ^ ((r & 7) << 3);
                gload_lds16(vbase + (size_t)r * 2048 + jn + cs, (char*)Vs + i * 4096 + w * 1024);
            }
        }
    }

    if (!split) {
        const float inv = 1.0f / l;
        unsigned short* orow = att + (size_t)(b * N_ + qrow) * 1024 + h * 64;
        #pragma unroll
        for (int dt = 0; dt < 4; ++dt) {
            #pragma unroll
            for (int rp = 0; rp < 2; ++rp) {
                const unsigned uu = cvt_pk_bf16(oacc[dt][2 * rp] * inv,
                                                oacc[dt][2 * rp + 1] * inv);
                *reinterpret_cast<unsigned*>(orow + dt * 16 + g * 4 + rp * 2) = uu;
            }
        }
    } else {
        const int slot = (bh * 16 + (qi - 16)) * 2 + half;
        const int rloc = w * 16 + c;
        pml[slot * 64 + rloc] = make_float2(m, l);
        unsigned short* prow = pO + (size_t)slot * 4096 + rloc * 64;
        #pragma unroll
        for (int dt = 0; dt < 4; ++dt) {
            #pragma unroll
            for (int rp = 0; rp < 2; ++rp) {
                const unsigned uu = cvt_pk_bf16(oacc[dt][2 * rp], oacc[dt][2 * rp + 1]);
                *reinterpret_cast<unsigned*>(prow + dt * 16 + g * 4 + rp * 2) = uu;
            }
        }
    }
}

// ---------------- merge split-KV partials ----------------
__global__ __launch_bounds__(256) void attn_merge_kernel(const unsigned short* __restrict__ pO,
                                                         const float2* __restrict__ pml,
                                                         unsigned short* __restrict__ att) {
    const int blk = blockIdx.x;        // 0..511 = bh*16 + qt
    const int bh = blk >> 4;
    const int qt = blk & 15;
    const int qi = 16 + qt;
    const int b = bh >> 4, h = bh & 15;
    const int tid = threadIdx.x;
    const int row = tid >> 2;
    const int d0 = (tid & 3) * 16;
    const int slot0 = (bh * 16 + qt) * 2;
    const float2 ml0 = pml[slot0 * 64 + row];
    const float2 ml1 = pml[(slot0 + 1) * 64 + row];
    const float M = fmaxf(ml0.x, ml1.x);
    const float w0 = exp2_fast(ml0.x - M);
    const float w1 = exp2_fast(ml1.x - M);
    const float invL = 1.0f / (ml0.y * w0 + ml1.y * w1);
    const unsigned short* p0 = pO + (size_t)slot0 * 4096 + row * 64 + d0;
    const unsigned short* p1 = p0 + 4096;
    const int qrow = qi * 64 + row;
    unsigned short* orow = att + (size_t)(b * N_ + qrow) * 1024 + h * 64 + d0;
    #pragma unroll
    for (int j = 0; j < 16; j += 2) {
        const float a0 = (bf2f(p0[j]) * w0 + bf2f(p1[j]) * w1) * invL;
        const float a1 = (bf2f(p0[j + 1]) * w0 + bf2f(p1[j + 1]) * w1) * invL;
        *reinterpret_cast<unsigned*>(orow + j) = cvt_pk_bf16(a0, a1);
    }
}

extern "C" void kernel_launch(void* const* d_in, const int* in_sizes, int n_in,
                              void* d_out, int out_size, void* d_ws, size_t ws_size,
                              hipStream_t stream) {
    const float* x     = (const float*)d_in[0];
    const float* pos   = (const float*)d_in[1];
    const float* gamma = (const float*)d_in[2];
    const float* Wq    = (const float*)d_in[3];
    const float* Wkv   = (const float*)d_in[4];
    const float* Wo    = (const float*)d_in[5];
    const float* bo    = (const float*)d_in[6];
    float* out = (float*)d_out;
    char* ws = (char*)d_ws;

    const size_t MB = 1024 * 1024;
    unsigned short* kb   = (unsigned short*)(ws);             // 8 MB roped K
    unsigned short* qb   = (unsigned short*)(ws + 16 * MB);   // 8 MB roped+scaled Q
    unsigned short* att  = (unsigned short*)(ws + 24 * MB);   // 8 MB attention output
    unsigned short* xb   = (unsigned short*)(ws + 32 * MB);   // 8 MB bf16 x (dead after qkv)
    unsigned short* Wqt  = (unsigned short*)(ws + 40 * MB);   // 2 MB
    unsigned short* Wkvt = (unsigned short*)(ws + 42 * MB);   // 4 MB
    unsigned short* Wot  = (unsigned short*)(ws + 46 * MB);   // 2 MB
    unsigned short* vt   = (unsigned short*)(ws + 48 * MB);   // 8 MB V^T [bh][d][pos]
    float2* tabq         = (float2*)(ws + 56 * MB);           // 1 MB
    float2* tabk         = (float2*)(ws + 57 * MB);           // 1 MB
    float* sv            = (float*)(ws + 58 * MB);            // 16 KB
    unsigned short* pO   = (unsigned short*)(ws + 32 * MB);   // 8.4 MB (overlay)
    float2* pml          = (float2*)(ws + 40 * MB + 512 * 1024);  // 512 KB

    freqtab_kernel<<<512, 256, 0, stream>>>(pos, tabq, tabk);
    convT_all_kernel<<<dim3(128, 32), 256, 0, stream>>>(Wq, Wkv, Wo, gamma, Wqt, Wkvt, Wot);
    rmsnorm_kernel<<<B_ * N_, 256, 0, stream>>>(x, xb, sv);

    gemm_qkv_kernel<<<1536, 256, 0, stream>>>(
        xb, Wqt, Wkvt, sv, qb, kb, vt, tabq, tabk);

    attn_mfma_kernel<<<1536, 256, 0, stream>>>(qb, kb, vt, att, pO, pml);
    attn_merge_kernel<<<512, 256, 0, stream>>>(pO, pml, att);

    gemm_o_kernel<<<512, 256, 0, stream>>>(att, Wot, bo, out);
}

// Round 20
// 106.066 us; speedup vs baseline: 1.1527x; 1.0703x over previous
//
#include <hip/hip_runtime.h>
#include <cmath>

#define B_ 2
#define N_ 2048
#define D_ 1024
#define H_ 16

typedef __attribute__((ext_vector_type(8))) short short8;
typedef __attribute__((ext_vector_type(4))) float f32x4;
typedef __attribute__((ext_vector_type(4))) unsigned short u16x4;
typedef __attribute__((ext_vector_type(4))) unsigned int uint4v;

__device__ __forceinline__ unsigned short f2bf(float f) {
    union { float f; unsigned u; } x;
    x.f = f;
    unsigned r = x.u + 0x7FFFu + ((x.u >> 16) & 1u);
    return (unsigned short)(r >> 16);
}
__device__ __forceinline__ float bf2f(unsigned short u) {
    union { unsigned u; float f; } x;
    x.u = ((unsigned)u) << 16;
    return x.f;
}
__device__ __forceinline__ unsigned cvt_pk_bf16(float lo, float hi) {
    unsigned r;
    asm("v_cvt_pk_bf16_f32 %0, %1, %2" : "=v"(r) : "v"(lo), "v"(hi));
    return r;
}
__device__ __forceinline__ float exp2_fast(float x) {
    float r;
    asm("v_exp_f32 %0, %1" : "=v"(r) : "v"(x));
    return r;
}
__device__ __forceinline__ void gload_lds16(const void* g, void* l) {
    __builtin_amdgcn_global_load_lds((const __attribute__((address_space(1))) unsigned*)g,
                                     (__attribute__((address_space(3))) unsigned*)l,
                                     16, 0, 0);
}

// ---------------- fused prologue: convT (bid<4096) | rmsnorm (4096..8191) | freqtab (8192..8703) ----
__global__ __launch_bounds__(256) void prologue_kernel(const float* __restrict__ x,
                                                       const float* __restrict__ pos,
                                                       const float* __restrict__ gamma,
                                                       const float* __restrict__ Wq,
                                                       const float* __restrict__ Wkv,
                                                       const float* __restrict__ Wo,
                                                       unsigned short* __restrict__ xb,
                                                       float* __restrict__ s,
                                                       float2* __restrict__ tabq,
                                                       float2* __restrict__ tabk,
                                                       unsigned short* __restrict__ Wqt,
                                                       unsigned short* __restrict__ Wkvt,
                                                       unsigned short* __restrict__ Wot) {
    __shared__ float tile[32][33];
    __shared__ float wss[4];
    const int bid = blockIdx.x;
    if (bid < 4096) {
        // weight transpose (gamma folded into Wq)
        const int bx = bid & 127;          // 0..127 over concat {Wq:32, Wkv:64, Wo:32}
        const int k0 = (bid >> 7) * 32;    // 0..992
        const float* W;
        unsigned short* Wt;
        int Nm, n0;
        bool gmul = false;
        if (bx < 32)       { W = Wq;  Wt = Wqt;  Nm = 1024; n0 = bx * 32; gmul = true; }
        else if (bx < 96)  { W = Wkv; Wt = Wkvt; Nm = 2048; n0 = (bx - 32) * 32; }
        else               { W = Wo;  Wt = Wot;  Nm = 1024; n0 = (bx - 96) * 32; }
        const int r = threadIdx.x >> 3, c4 = (threadIdx.x & 7) * 4;
        const float4 ld = *reinterpret_cast<const float4*>(W + (size_t)(k0 + r) * Nm + n0 + c4);
        tile[r][c4 + 0] = ld.x; tile[r][c4 + 1] = ld.y;
        tile[r][c4 + 2] = ld.z; tile[r][c4 + 3] = ld.w;
        __syncthreads();
        u16x4 o;
        #pragma unroll
        for (int j = 0; j < 4; ++j) {
            float v = tile[c4 + j][r];
            if (gmul) v *= gamma[k0 + c4 + j];
            o[j] = f2bf(v);
        }
        *reinterpret_cast<u16x4*>(Wt + (size_t)(n0 + r) * 1024 + k0 + c4) = o;
    } else if (bid < 8192) {
        // RMS-like norm: bf16 x copy + per-row scale
        const int row = bid - 4096;
        const float4 v = reinterpret_cast<const float4*>(x + (size_t)row * D_)[threadIdx.x];
        float ss = v.x * v.x + v.y * v.y + v.z * v.z + v.w * v.w;
        #pragma unroll
        for (int off = 32; off; off >>= 1) ss += __shfl_xor(ss, off, 64);
        if ((threadIdx.x & 63) == 0) wss[threadIdx.x >> 6] = ss;
        __syncthreads();
        const float tot = wss[0] + wss[1] + wss[2] + wss[3];
        const float inv = 1.0f / fmaxf(sqrtf(tot * (1.0f / D_)), 1e-8f);
        if (threadIdx.x == 0) s[row] = inv;
        u16x4 ox;
        ox[0] = f2bf(v.x); ox[1] = f2bf(v.y); ox[2] = f2bf(v.z); ox[3] = f2bf(v.w);
        *reinterpret_cast<u16x4*>(xb + (size_t)row * D_ + threadIdx.x * 4) = ox;
    } else {
        // cos/sin tables (q table pre-scaled by 0.125*log2e)
        const int idx = (bid - 8192) * 256 + threadIdx.x;   // < 131072
        const float f = pos[idx];
        const float cc = cosf(f), ssn = sinf(f);
        const float sq = 0.125f * 1.4426950408889634f;
        tabq[idx] = make_float2(sq * cc, sq * ssn);
        tabk[idx] = make_float2(cc, ssn);
    }
}

// ---------------- merged q + kv GEMM: BM=64, BN=128, BK=64, A dbuf + B single, 33KB LDS --------
// grid 1536 = 8 XCD x 3 panels x 64 m-tiles. xcd=bid&7 owns bx in [3*xcd, 3*xcd+3); within an
// XCD the panel index changes fastest so consecutive blocks share the same A tile (L2-hot).
// Pipeline: head = issue A[t+1] (2 loads) + vmcnt(2) (A[t],B[t] landed; A[t+1] flying);
// tail (after compute barrier) = issue B[t+1] (4 loads) into the single B buffer — B-panel is
// XCD-L2-resident so its latency hides under the next head+compute.
// bx 0-7: q -> qb (rope tabq, s-scaled); 8-15: K -> kb (rope tabk);
// 16-23: V -> vt with within-64-tile KEY PERMUTATION (pos bits = wm,gg1,gg0,mf,reg) so
// attention's PV B-operand is lane-local (see attn kernel).
__global__ __launch_bounds__(256, 4) void gemm_qkv_kernel(const unsigned short* __restrict__ xb,
                                                          const unsigned short* __restrict__ Wqt,
                                                          const unsigned short* __restrict__ Wkvt,
                                                          const float* __restrict__ s,
                                                          unsigned short* __restrict__ qb,
                                                          unsigned short* __restrict__ kb,
                                                          unsigned short* __restrict__ vt,
                                                          const float2* __restrict__ tabq,
                                                          const float2* __restrict__ tabk) {
    __shared__ unsigned short As[2][64 * 64];    // 8KB each
    __shared__ unsigned short Bs[128 * 64];      // 16KB single
    __shared__ float sld[64];
    const int bid = blockIdx.x;
    const int xcd = bid & 7;
    const int ii = bid >> 3;                 // 0..191
    const int bx = xcd * 3 + (ii % 3);       // 0..23
    const int m0 = (ii / 3) * 64;            // 0..4032

    const unsigned short* Bt;
    int n0;
    if (bx < 8)       { Bt = Wqt;  n0 = bx * 128; }
    else if (bx < 16) { Bt = Wkvt; n0 = (bx - 8) * 128; }
    else              { Bt = Wkvt; n0 = (bx - 16) * 128 + 1024; }

    const int tid = threadIdx.x, lane = tid & 63, w = tid >> 6;
    const int wm = w >> 1, wn = w & 1;       // wave tile 32 x 64
    const int cc = lane & 15;
    const int sr = tid >> 3;                 // 0..31
    const int sc = (tid & 7) * 8;

    if (tid < 64) sld[tid] = s[m0 + tid];

    f32x4 acc[2][4] = {};

    // prologue: stage A0 (2 loads) then B0 (4 loads)
    #pragma unroll
    for (int i = 0; i < 2; ++i) {
        const int r = i * 32 + sr;
        const int cs = sc ^ ((r & 7) << 3);
        gload_lds16(xb + (size_t)(m0 + r) * 1024 + cs, (char*)As[0] + i * 4096 + w * 1024);
    }
    #pragma unroll
    for (int i = 0; i < 4; ++i) {
        const int r = i * 32 + sr;
        const int cs = sc ^ ((r & 7) << 3);
        gload_lds16(Bt + (size_t)(n0 + r) * 1024 + cs, (char*)Bs + i * 4096 + w * 1024);
    }

    for (int t = 0; t < 16; ++t) {
        if (t + 1 < 16) {
            const int k0 = (t + 1) * 64;
            char* ad = (char*)As[(t + 1) & 1];
            #pragma unroll
            for (int i = 0; i < 2; ++i) {
                const int r = i * 32 + sr;
                const int cs = sc ^ ((r & 7) << 3);
                gload_lds16(xb + (size_t)(m0 + r) * 1024 + k0 + cs, ad + i * 4096 + w * 1024);
            }
            asm volatile("s_waitcnt vmcnt(2)" ::: "memory");  // A[t],B[t] landed; A[t+1] flying
        } else {
            asm volatile("s_waitcnt vmcnt(0)" ::: "memory");
        }
        __builtin_amdgcn_s_barrier();

        const char* Ac = (const char*)As[t & 1];
        const char* Bc = (const char*)Bs;

        short8 af[2][2], bf[4][2];
        #pragma unroll
        for (int mf = 0; mf < 2; ++mf)
            #pragma unroll
            for (int ks = 0; ks < 2; ++ks) {
                const int r = wm * 32 + mf * 16 + cc;
                const int cb = (ks * 64 + ((lane >> 4) * 16)) ^ ((r & 7) << 4);
                af[mf][ks] = *reinterpret_cast<const short8*>(Ac + r * 128 + cb);
            }
        #pragma unroll
        for (int nf = 0; nf < 4; ++nf)
            #pragma unroll
            for (int ks = 0; ks < 2; ++ks) {
                const int r = wn * 64 + nf * 16 + cc;
                const int cb = (ks * 64 + ((lane >> 4) * 16)) ^ ((r & 7) << 4);
                bf[nf][ks] = *reinterpret_cast<const short8*>(Bc + r * 128 + cb);
            }
        #pragma unroll
        for (int ks = 0; ks < 2; ++ks)
            #pragma unroll
            for (int mf = 0; mf < 2; ++mf)
                #pragma unroll
                for (int nf = 0; nf < 4; ++nf)
                    acc[mf][nf] = __builtin_amdgcn_mfma_f32_16x16x32_bf16(af[mf][ks], bf[nf][ks], acc[mf][nf], 0, 0, 0);

        __builtin_amdgcn_s_barrier();   // all waves done reading As[t&1] / Bs

        if (t + 1 < 16) {               // stage B[t+1] into the single B buffer
            const int k0 = (t + 1) * 64;
            #pragma unroll
            for (int i = 0; i < 4; ++i) {
                const int r = i * 32 + sr;
                const int cs = sc ^ ((r & 7) << 3);
                gload_lds16(Bt + (size_t)(n0 + r) * 1024 + k0 + cs, (char*)Bs + i * 4096 + w * 1024);
            }
        }
    }

    if (bx < 16) {
        // rope epilogue; q additionally scaled by per-row s (f32). Head = 64-col span (wn half).
        const float2* tab = (bx < 8) ? tabq : tabk;
        unsigned short* dst = (bx < 8) ? qb : kb;
        const bool doscale = (bx < 8);
        #pragma unroll
        for (int mf = 0; mf < 2; ++mf)
            #pragma unroll
            for (int reg = 0; reg < 4; ++reg) {
                const int rloc = wm * 32 + mf * 16 + (lane >> 4) * 4 + reg;
                const int row = m0 + rloc;
                const int n = row & (N_ - 1);
                const float srow = doscale ? sld[rloc] : 1.0f;
                #pragma unroll
                for (int nf = 0; nf < 2; ++nf) {
                    const int d = nf * 16 + cc;
                    const float2 t1 = tab[n * 64 + d];
                    const float2 t2 = tab[n * 64 + 32 + d];
                    const float x1 = acc[mf][nf][reg] * srow;
                    const float x2 = acc[mf][nf + 2][reg] * srow;
                    const float o1 = x1 * t1.x - x2 * t1.y;
                    const float o2 = x2 * t2.x + x1 * t2.y;
                    const int col = n0 + wn * 64 + nf * 16 + cc;
                    dst[(size_t)row * 1024 + col] = f2bf(o1);
                    dst[(size_t)row * 1024 + col + 32] = f2bf(o2);
                }
            }
    } else {
        // V: store transposed into vt[bh*64+d][pos], pos = within-64-tile key permutation:
        // key bits (wm, mf, gg1, gg0, reg1, reg0) -> pos = wm*32 + gg1*16 + gg0*8 + mf*4 + reg
        const int bb = m0 >> 11;                 // batch
        const int gg = lane >> 4;
        const int tb = m0 & (N_ - 1);            // 64-aligned tile base
        #pragma unroll
        for (int mf = 0; mf < 2; ++mf) {
            const int npos = tb + wm * 32 + (gg >> 1) * 16 + (gg & 1) * 8 + mf * 4;
            #pragma unroll
            for (int nf = 0; nf < 4; ++nf) {
                const int cv = n0 - 1024 + wn * 64 + nf * 16 + cc;   // 0..1023
                const int h = cv >> 6, d = cv & 63;
                uint2 u;
                u.x = cvt_pk_bf16(acc[mf][nf][0], acc[mf][nf][1]);
                u.y = cvt_pk_bf16(acc[mf][nf][2], acc[mf][nf][3]);
                *reinterpret_cast<uint2*>(vt + ((size_t)(bb * 16 + h) * 64 + d) * 2048 + npos) = u;
            }
        }
    }
}

// ---------------- output GEMM: C = att @ Wot^T + bo (f32 out), BN=64, XCD-affine, dbuf ----------------
__global__ __launch_bounds__(256) void gemm_o_kernel(const unsigned short* __restrict__ A,
                                                     const unsigned short* __restrict__ Bt,
                                                     const float* __restrict__ bias,
                                                     float* __restrict__ Cout) {
    __shared__ unsigned short As[2][128 * 64];
    __shared__ unsigned short Bs[2][64 * 64];
    const int bid = blockIdx.x;
    const int xcd = bid & 7;
    const int ii = bid >> 3;
    const int n0 = (xcd * 2 + (ii & 1)) * 64;
    const int m0 = (ii >> 1) * 128;
    const int tid = threadIdx.x, lane = tid & 63, w = tid >> 6;
    const int wm = w >> 1, wn = w & 1;
    const int cc = lane & 15;
    const int sr = tid >> 3;
    const int sc = (tid & 7) * 8;

    f32x4 acc[4][2] = {};

    #pragma unroll
    for (int i = 0; i < 4; ++i) {
        const int r = i * 32 + sr;
        const int cs = sc ^ ((r & 7) << 3);
        gload_lds16(A + (size_t)(m0 + r) * 1024 + cs, (char*)As[0] + i * 4096 + w * 1024);
        if (i < 2)
            gload_lds16(Bt + (size_t)(n0 + r) * 1024 + cs, (char*)Bs[0] + i * 4096 + w * 1024);
    }

    for (int t = 0; t < 16; ++t) {
        if (t + 1 < 16) {
            const int k0 = (t + 1) * 64;
            char* ad = (char*)As[(t + 1) & 1];
            char* bd = (char*)Bs[(t + 1) & 1];
            #pragma unroll
            for (int i = 0; i < 4; ++i) {
                const int r = i * 32 + sr;
                const int cs = sc ^ ((r & 7) << 3);
                gload_lds16(A + (size_t)(m0 + r) * 1024 + k0 + cs, ad + i * 4096 + w * 1024);
                if (i < 2)
                    gload_lds16(Bt + (size_t)(n0 + r) * 1024 + k0 + cs, bd + i * 4096 + w * 1024);
            }
            asm volatile("s_waitcnt vmcnt(6)" ::: "memory");
        } else {
            asm volatile("s_waitcnt vmcnt(0)" ::: "memory");
        }
        __builtin_amdgcn_s_barrier();

        const char* Ac = (const char*)As[t & 1];
        const char* Bc = (const char*)Bs[t & 1];

        short8 af[4][2], bf[2][2];
        #pragma unroll
        for (int mf = 0; mf < 4; ++mf)
            #pragma unroll
            for (int ks = 0; ks < 2; ++ks) {
                const int r = wm * 64 + mf * 16 + cc;
                const int cb = (ks * 64 + ((lane >> 4) * 16)) ^ ((r & 7) << 4);
                af[mf][ks] = *reinterpret_cast<const short8*>(Ac + r * 128 + cb);
            }
        #pragma unroll
        for (int nf = 0; nf < 2; ++nf)
            #pragma unroll
            for (int ks = 0; ks < 2; ++ks) {
                const int r = wn * 32 + nf * 16 + cc;
                const int cb = (ks * 64 + ((lane >> 4) * 16)) ^ ((r & 7) << 4);
                bf[nf][ks] = *reinterpret_cast<const short8*>(Bc + r * 128 + cb);
            }
        #pragma unroll
        for (int ks = 0; ks < 2; ++ks)
            #pragma unroll
            for (int mf = 0; mf < 4; ++mf)
                #pragma unroll
                for (int nf = 0; nf < 2; ++nf)
                    acc[mf][nf] = __builtin_amdgcn_mfma_f32_16x16x32_bf16(af[mf][ks], bf[nf][ks], acc[mf][nf], 0, 0, 0);

        __builtin_amdgcn_s_barrier();
    }

    float bb[2];
    #pragma unroll
    for (int nf = 0; nf < 2; ++nf) bb[nf] = bias[n0 + wn * 32 + nf * 16 + cc];
    #pragma unroll
    for (int mf = 0; mf < 4; ++mf)
        #pragma unroll
        for (int nf = 0; nf < 2; ++nf)
            #pragma unroll
            for (int reg = 0; reg < 4; ++reg) {
                const int row = m0 + wm * 64 + mf * 16 + (lane >> 4) * 4 + reg;
                const int col = n0 + wn * 32 + nf * 16 + cc;
                Cout[(size_t)row * 1024 + col] = acc[mf][nf][reg] + bb[nf];
            }
}

// ---------------- bf16 MFMA causal flash attention, split-KV, 24KB LDS, P fully in-register ----
// grid 1536. xcd=bid&7 (bh affinity). Balanced CU mapping: co-resident blocks (same u=rest&31,
// v=0..5) get one complementary pair from each work class -> per-CU work 65-67 units:
//   v pair (0,1): unsplit s = p / 15-p; v pair (2,3): split-low; v pair (4,5): split-high.
// s<16: unsplit qi=s; s>=16: split halves -> pO/pml + merge.
__global__ __launch_bounds__(256, 6) void attn_mfma_kernel(const unsigned short* __restrict__ q,
                                                           const unsigned short* __restrict__ kb,
                                                           const unsigned short* __restrict__ vt,
                                                           unsigned short* __restrict__ att,
                                                           unsigned short* __restrict__ pO,
                                                           float2* __restrict__ pml) {
    const int bid = blockIdx.x;
    const int xcd = bid & 7;
    const int rest = bid >> 3;          // 0..191
    const int v = rest >> 5;            // 0..5
    const int u = rest & 31;            // 0..31
    const int a = u >> 4;               // 0..1
    const int p = u & 15;               // 0..15
    const int bh = xcd * 4 + 2 * a + (v & 1);
    const int s = (v >> 1) * 16 + ((v & 1) ? (15 - p) : p);
    int qi, t0, t1, half;
    bool split;
    if (s < 16) {
        qi = s; t0 = 0; t1 = qi + 1; half = 0; split = false;
    } else {
        const int qs = s - 16;
        qi = 16 + (qs >> 1);
        half = qs & 1;
        const int hmid = (qi + 2) >> 1;
        t0 = half ? hmid : 0;
        t1 = half ? (qi + 1) : hmid;
        split = true;
    }
    const int b = bh >> 4, h = bh & 15;
    const int qb_ = qi * 64;
    const int tid = threadIdx.x;
    const int lane = tid & 63;
    const int w = tid >> 6;
    const int c = lane & 15;
    const int g = lane >> 4;

    __shared__ __align__(16) unsigned short Ks[2][64 * 64];   // [key][d] swizzled (dbuf, 16KB)
    __shared__ __align__(16) unsigned short Vs[64 * 64];      // [d][key-pos] swizzled (8KB)

    const int qrow = qb_ + w * 16 + c;
    short8 qf[2];
    {
        const unsigned short* qp = q + (size_t)(b * N_ + qrow) * 1024 + h * 64 + g * 8;
        qf[0] = *reinterpret_cast<const short8*>(qp);
        qf[1] = *reinterpret_cast<const short8*>(qp + 32);
    }

    float m = -1e30f, l = 0.f;
    f32x4 oacc[4] = {};

    const int sr = tid >> 3, sc = (tid & 7) * 8;
    const unsigned short* kbase = kb + (size_t)b * N_ * 1024 + h * 64;
    const unsigned short* vbase = vt + (size_t)bh * 64 * 2048;

    // prologue: stage K[t0] into buf (t0&1), V[t0] into the single V buffer
    #pragma unroll
    for (int i = 0; i < 2; ++i) {
        const int r = i * 32 + sr;
        const int cs = sc ^ ((r & 7) << 3);
        gload_lds16(kbase + (size_t)(t0 * 64 + r) * 1024 + cs,
                    (char*)Ks[t0 & 1] + i * 4096 + w * 1024);
        gload_lds16(vbase + (size_t)r * 2048 + t0 * 64 + cs,
                    (char*)Vs + i * 4096 + w * 1024);
    }

    for (int t = t0; t < t1; ++t) {
        const int jb = t * 64;
        const int jn = jb + 64;
        if (t + 1 < t1) {
            char* kd = (char*)Ks[(t + 1) & 1];
            #pragma unroll
            for (int i = 0; i < 2; ++i) {
                const int r = i * 32 + sr;
                const int cs = sc ^ ((r & 7) << 3);
                gload_lds16(kbase + (size_t)(jn + r) * 1024 + cs, kd + i * 4096 + w * 1024);
            }
            asm volatile("s_waitcnt vmcnt(2)" ::: "memory");  // K[t],V[t] landed; K[t+1] flying
        } else {
            asm volatile("s_waitcnt vmcnt(0)" ::: "memory");
        }
        __builtin_amdgcn_s_barrier();

        const char* Ksc = (const char*)Ks[t & 1];
        const char* Vsc = (const char*)Vs;

        f32x4 st[4];
        __builtin_amdgcn_s_setprio(1);
        #pragma unroll
        for (int ct = 0; ct < 4; ++ct) {
            const int key = ct * 16 + c;
            f32x4 acc = {0.f, 0.f, 0.f, 0.f};
            #pragma unroll
            for (int ks = 0; ks < 2; ++ks) {
                const int addr = (key * 128 + ks * 64 + g * 16) ^ ((key & 7) << 4);
                const short8 kf = *reinterpret_cast<const short8*>(Ksc + addr);
                acc = __builtin_amdgcn_mfma_f32_16x16x32_bf16(kf, qf[ks], acc, 0, 0, 0);
            }
            st[ct] = acc;
        }
        __builtin_amdgcn_s_setprio(0);

        // exp2-domain online softmax with defer-max (lane owns row qrow; key = jb+ct*16+g*4+reg)
        float mx = -1e30f;
        if (jb + 63 > qrow) {
            #pragma unroll
            for (int ct = 0; ct < 4; ++ct)
                #pragma unroll
                for (int reg = 0; reg < 4; ++reg) {
                    const int key = jb + ct * 16 + g * 4 + reg;
                    const float sv = (key <= qrow) ? st[ct][reg] : -1e30f;
                    st[ct][reg] = sv;
                    mx = fmaxf(mx, sv);
                }
        } else {
            #pragma unroll
            for (int ct = 0; ct < 4; ++ct)
                mx = fmaxf(mx, fmaxf(fmaxf(st[ct][0], st[ct][1]),
                                     fmaxf(st[ct][2], st[ct][3])));
        }
        mx = fmaxf(mx, __shfl_xor(mx, 16, 64));
        mx = fmaxf(mx, __shfl_xor(mx, 32, 64));
        if (!__all(mx <= m + 8.0f)) {
            const float mn = fmaxf(m, mx);
            const float corr = exp2_fast(m - mn);
            l *= corr;
            m = mn;
            #pragma unroll
            for (int dt = 0; dt < 4; ++dt) {
                oacc[dt][0] *= corr; oacc[dt][1] *= corr;
                oacc[dt][2] *= corr; oacc[dt][3] *= corr;
            }
        }
        float rs = 0.f;
        #pragma unroll
        for (int ct = 0; ct < 4; ++ct)
            #pragma unroll
            for (int reg = 0; reg < 4; ++reg) {
                const float p2 = exp2_fast(st[ct][reg] - m);
                st[ct][reg] = p2;
                rs += p2;
            }
        rs += __shfl_xor(rs, 16, 64);
        rs += __shfl_xor(rs, 32, 64);
        l += rs;

        // P -> bf16 fully in-register (no LDS round trip)
        uint4v pv0, pv1;
        pv0[0] = cvt_pk_bf16(st[0][0], st[0][1]);
        pv0[1] = cvt_pk_bf16(st[0][2], st[0][3]);
        pv0[2] = cvt_pk_bf16(st[1][0], st[1][1]);
        pv0[3] = cvt_pk_bf16(st[1][2], st[1][3]);
        pv1[0] = cvt_pk_bf16(st[2][0], st[2][1]);
        pv1[1] = cvt_pk_bf16(st[2][2], st[2][3]);
        pv1[2] = cvt_pk_bf16(st[3][0], st[3][1]);
        pv1[3] = cvt_pk_bf16(st[3][2], st[3][3]);
        const short8 pf0 = *reinterpret_cast<const short8*>(&pv0);
        const short8 pf1 = *reinterpret_cast<const short8*>(&pv1);

        // O^T += V^T · P^T  (vf positions hold permuted keys matching pf's element keys)
        __builtin_amdgcn_s_setprio(1);
        #pragma unroll
        for (int dt = 0; dt < 4; ++dt) {
            const int vd = dt * 16 + c;
            {
                const int addr = (vd * 128 + 0 * 64 + g * 16) ^ ((vd & 7) << 4);
                const short8 vf = *reinterpret_cast<const short8*>(Vsc + addr);
                oacc[dt] = __builtin_amdgcn_mfma_f32_16x16x32_bf16(vf, pf0, oacc[dt], 0, 0, 0);
            }
            {
                const int addr = (vd * 128 + 1 * 64 + g * 16) ^ ((vd & 7) << 4);
                const short8 vf = *reinterpret_cast<const short8*>(Vsc + addr);
                oacc[dt] = __builtin_amdgcn_mfma_f32_16x16x32_bf16(vf, pf1, oacc[dt], 0, 0, 0);
            }
        }
        __builtin_amdgcn_s_setprio(0);

        __builtin_amdgcn_s_barrier();   // all waves done reading Vs / Ks[t&1]

        if (t + 1 < t1) {   // stage V[t+1] into the single V buffer
            #pragma unroll
            for (int i = 0; i < 2; ++i) {
                const int r = i * 32 + sr;
                const int cs = sc ^ ((r & 7) << 3);
                gload_lds16(vbase + (size_t)r * 2048 + jn + cs, (char*)Vs + i * 4096 + w * 1024);
            }
        }
    }

    if (!split) {
        const float inv = 1.0f / l;
        unsigned short* orow = att + (size_t)(b * N_ + qrow) * 1024 + h * 64;
        #pragma unroll
        for (int dt = 0; dt < 4; ++dt) {
            #pragma unroll
            for (int rp = 0; rp < 2; ++rp) {
                const unsigned uu = cvt_pk_bf16(oacc[dt][2 * rp] * inv,
                                                oacc[dt][2 * rp + 1] * inv);
                *reinterpret_cast<unsigned*>(orow + dt * 16 + g * 4 + rp * 2) = uu;
            }
        }
    } else {
        const int slot = (bh * 16 + (qi - 16)) * 2 + half;
        const int rloc = w * 16 + c;
        pml[slot * 64 + rloc] = make_float2(m, l);
        unsigned short* prow = pO + (size_t)slot * 4096 + rloc * 64;
        #pragma unroll
        for (int dt = 0; dt < 4; ++dt) {
            #pragma unroll
            for (int rp = 0; rp < 2; ++rp) {
                const unsigned uu = cvt_pk_bf16(oacc[dt][2 * rp], oacc[dt][2 * rp + 1]);
                *reinterpret_cast<unsigned*>(prow + dt * 16 + g * 4 + rp * 2) = uu;
            }
        }
    }
}

// ---------------- merge split-KV partials ----------------
__global__ __launch_bounds__(256) void attn_merge_kernel(const unsigned short* __restrict__ pO,
                                                         const float2* __restrict__ pml,
                                                         unsigned short* __restrict__ att) {
    const int blk = blockIdx.x;        // 0..511 = bh*16 + qt
    const int bh = blk >> 4;
    const int qt = blk & 15;
    const int qi = 16 + qt;
    const int b = bh >> 4, h = bh & 15;
    const int tid = threadIdx.x;
    const int row = tid >> 2;
    const int d0 = (tid & 3) * 16;
    const int slot0 = (bh * 16 + qt) * 2;
    const float2 ml0 = pml[slot0 * 64 + row];
    const float2 ml1 = pml[(slot0 + 1) * 64 + row];
    const float M = fmaxf(ml0.x, ml1.x);
    const float w0 = exp2_fast(ml0.x - M);
    const float w1 = exp2_fast(ml1.x - M);
    const float invL = 1.0f / (ml0.y * w0 + ml1.y * w1);
    const unsigned short* p0 = pO + (size_t)slot0 * 4096 + row * 64 + d0;
    const unsigned short* p1 = p0 + 4096;
    const int qrow = qi * 64 + row;
    unsigned short* orow = att + (size_t)(b * N_ + qrow) * 1024 + h * 64 + d0;
    #pragma unroll
    for (int j = 0; j < 16; j += 2) {
        const float a0 = (bf2f(p0[j]) * w0 + bf2f(p1[j]) * w1) * invL;
        const float a1 = (bf2f(p0[j + 1]) * w0 + bf2f(p1[j + 1]) * w1) * invL;
        *reinterpret_cast<unsigned*>(orow + j) = cvt_pk_bf16(a0, a1);
    }
}

extern "C" void kernel_launch(void* const* d_in, const int* in_sizes, int n_in,
                              void* d_out, int out_size, void* d_ws, size_t ws_size,
                              hipStream_t stream) {
    const float* x     = (const float*)d_in[0];
    const float* pos   = (const float*)d_in[1];
    const float* gamma = (const float*)d_in[2];
    const float* Wq    = (const float*)d_in[3];
    const float* Wkv   = (const float*)d_in[4];
    const float* Wo    = (const float*)d_in[5];
    const float* bo    = (const float*)d_in[6];
    float* out = (float*)d_out;
    char* ws = (char*)d_ws;

    const size_t MB = 1024 * 1024;
    unsigned short* kb   = (unsigned short*)(ws);             // 8 MB roped K
    unsigned short* qb   = (unsigned short*)(ws + 16 * MB);   // 8 MB roped+scaled Q
    unsigned short* att  = (unsigned short*)(ws + 24 * MB);   // 8 MB attention output
    unsigned short* xb   = (unsigned short*)(ws + 32 * MB);   // 8 MB bf16 x (dead after qkv)
    unsigned short* Wqt  = (unsigned short*)(ws + 40 * MB);   // 2 MB
    unsigned short* Wkvt = (unsigned short*)(ws + 42 * MB);   // 4 MB
    unsigned short* Wot  = (unsigned short*)(ws + 46 * MB);   // 2 MB
    unsigned short* vt   = (unsigned short*)(ws + 48 * MB);   // 8 MB V^T [bh][d][pos]
    float2* tabq         = (float2*)(ws + 56 * MB);           // 1 MB
    float2* tabk         = (float2*)(ws + 57 * MB);           // 1 MB
    float* sv            = (float*)(ws + 58 * MB);            // 16 KB
    unsigned short* pO   = (unsigned short*)(ws + 32 * MB);   // 8.4 MB (overlay, after qkv)
    float2* pml          = (float2*)(ws + 40 * MB + 512 * 1024);  // 512 KB

    prologue_kernel<<<8704, 256, 0, stream>>>(
        x, pos, gamma, Wq, Wkv, Wo, xb, sv, tabq, tabk, Wqt, Wkvt, Wot);

    gemm_qkv_kernel<<<1536, 256, 0, stream>>>(
        xb, Wqt, Wkvt, sv, qb, kb, vt, tabq, tabk);

    attn_mfma_kernel<<<1536, 256, 0, stream>>>(qb, kb, vt, att, pO, pml);
    attn_merge_kernel<<<512, 256, 0, stream>>>(pO, pml, att);

    gemm_o_kernel<<<512, 256, 0, stream>>>(att, Wot, bo, out);
}

// Round 21
// 101.126 us; speedup vs baseline: 1.2090x; 1.0489x over previous
//
#include <hip/hip_runtime.h>
#include <cmath>

#define B_ 2
#define N_ 2048
#define D_ 1024
#define H_ 16

typedef __attribute__((ext_vector_type(8))) short short8;
typedef __attribute__((ext_vector_type(4))) float f32x4;
typedef __attribute__((ext_vector_type(4))) unsigned short u16x4;
typedef __attribute__((ext_vector_type(4))) unsigned int uint4v;

__device__ __forceinline__ unsigned short f2bf(float f) {
    union { float f; unsigned u; } x;
    x.f = f;
    unsigned r = x.u + 0x7FFFu + ((x.u >> 16) & 1u);
    return (unsigned short)(r >> 16);
}
__device__ __forceinline__ float bf2f(unsigned short u) {
    union { unsigned u; float f; } x;
    x.u = ((unsigned)u) << 16;
    return x.f;
}
__device__ __forceinline__ unsigned cvt_pk_bf16(float lo, float hi) {
    unsigned r;
    asm("v_cvt_pk_bf16_f32 %0, %1, %2" : "=v"(r) : "v"(lo), "v"(hi));
    return r;
}
__device__ __forceinline__ float exp2_fast(float x) {
    float r;
    asm("v_exp_f32 %0, %1" : "=v"(r) : "v"(x));
    return r;
}
__device__ __forceinline__ void gload_lds16(const void* g, void* l) {
    __builtin_amdgcn_global_load_lds((const __attribute__((address_space(1))) unsigned*)g,
                                     (__attribute__((address_space(3))) unsigned*)l,
                                     16, 0, 0);
}

// ---------------- fused prologue: convT (bid<4096) | rmsnorm (4096..8191) | freqtab (8192..8703) ----
__global__ __launch_bounds__(256) void prologue_kernel(const float* __restrict__ x,
                                                       const float* __restrict__ pos,
                                                       const float* __restrict__ gamma,
                                                       const float* __restrict__ Wq,
                                                       const float* __restrict__ Wkv,
                                                       const float* __restrict__ Wo,
                                                       unsigned short* __restrict__ xb,
                                                       float* __restrict__ s,
                                                       float2* __restrict__ tabq,
                                                       float2* __restrict__ tabk,
                                                       unsigned short* __restrict__ Wqt,
                                                       unsigned short* __restrict__ Wkvt,
                                                       unsigned short* __restrict__ Wot) {
    __shared__ float tile[32][33];
    __shared__ float wss[4];
    const int bid = blockIdx.x;
    if (bid < 4096) {
        const int bx = bid & 127;
        const int k0 = (bid >> 7) * 32;
        const float* W;
        unsigned short* Wt;
        int Nm, n0;
        bool gmul = false;
        if (bx < 32)       { W = Wq;  Wt = Wqt;  Nm = 1024; n0 = bx * 32; gmul = true; }
        else if (bx < 96)  { W = Wkv; Wt = Wkvt; Nm = 2048; n0 = (bx - 32) * 32; }
        else               { W = Wo;  Wt = Wot;  Nm = 1024; n0 = (bx - 96) * 32; }
        const int r = threadIdx.x >> 3, c4 = (threadIdx.x & 7) * 4;
        const float4 ld = *reinterpret_cast<const float4*>(W + (size_t)(k0 + r) * Nm + n0 + c4);
        tile[r][c4 + 0] = ld.x; tile[r][c4 + 1] = ld.y;
        tile[r][c4 + 2] = ld.z; tile[r][c4 + 3] = ld.w;
        __syncthreads();
        u16x4 o;
        #pragma unroll
        for (int j = 0; j < 4; ++j) {
            float v = tile[c4 + j][r];
            if (gmul) v *= gamma[k0 + c4 + j];
            o[j] = f2bf(v);
        }
        *reinterpret_cast<u16x4*>(Wt + (size_t)(n0 + r) * 1024 + k0 + c4) = o;
    } else if (bid < 8192) {
        const int row = bid - 4096;
        const float4 v = reinterpret_cast<const float4*>(x + (size_t)row * D_)[threadIdx.x];
        float ss = v.x * v.x + v.y * v.y + v.z * v.z + v.w * v.w;
        #pragma unroll
        for (int off = 32; off; off >>= 1) ss += __shfl_xor(ss, off, 64);
        if ((threadIdx.x & 63) == 0) wss[threadIdx.x >> 6] = ss;
        __syncthreads();
        const float tot = wss[0] + wss[1] + wss[2] + wss[3];
        const float inv = 1.0f / fmaxf(sqrtf(tot * (1.0f / D_)), 1e-8f);
        if (threadIdx.x == 0) s[row] = inv;
        u16x4 ox;
        ox[0] = f2bf(v.x); ox[1] = f2bf(v.y); ox[2] = f2bf(v.z); ox[3] = f2bf(v.w);
        *reinterpret_cast<u16x4*>(xb + (size_t)row * D_ + threadIdx.x * 4) = ox;
    } else {
        const int idx = (bid - 8192) * 256 + threadIdx.x;
        const float f = pos[idx];
        const float cc = cosf(f), ssn = sinf(f);
        const float sq = 0.125f * 1.4426950408889634f;
        tabq[idx] = make_float2(sq * cc, sq * ssn);
        tabk[idx] = make_float2(cc, ssn);
    }
}

// ---------------- merged q + kv GEMM: BM=128, BN=128, BK=64, A dbuf + B single, 48.5KB LDS -----
// grid 768 = 8 XCD x 3 panels x 32 m-tiles = exactly 3 blocks/CU, no tail.
// Wave tile 64x64 (m97 density): 32 MFMA + 16 ds_read_b128 per step per wave.
// Pipeline: head = issue A[t+1] (4) + vmcnt(4) (A[t],B[t] landed; A[t+1] flying);
// tail (after compute barrier) = issue B[t+1] (4) into the single B buffer (B-panel L2-hot).
// bx 0-7: q -> qb (rope tabq, s-scaled); 8-15: K -> kb (rope tabk);
// 16-23: V -> vt, within-64-tile key permutation: key bits (mf1,mf0,g1,g0,r1,r0) ->
// pos = mf1*32 + g1*16 + g0*8 + mf0*4 + reg  (so attn's PV B-operand is lane-local).
__global__ __launch_bounds__(256, 3) void gemm_qkv_kernel(const unsigned short* __restrict__ xb,
                                                          const unsigned short* __restrict__ Wqt,
                                                          const unsigned short* __restrict__ Wkvt,
                                                          const float* __restrict__ s,
                                                          unsigned short* __restrict__ qb,
                                                          unsigned short* __restrict__ kb,
                                                          unsigned short* __restrict__ vt,
                                                          const float2* __restrict__ tabq,
                                                          const float2* __restrict__ tabk) {
    __shared__ unsigned short As[2][128 * 64];   // 16KB each
    __shared__ unsigned short Bs[128 * 64];      // 16KB single
    __shared__ float sld[128];
    const int bid = blockIdx.x;
    const int xcd = bid & 7;
    const int ii = bid >> 3;                 // 0..95
    const int bx = xcd * 3 + (ii % 3);       // 0..23
    const int m0 = (ii / 3) * 128;           // 0..3968

    const unsigned short* Bt;
    int n0;
    if (bx < 8)       { Bt = Wqt;  n0 = bx * 128; }
    else if (bx < 16) { Bt = Wkvt; n0 = (bx - 8) * 128; }
    else              { Bt = Wkvt; n0 = (bx - 16) * 128 + 1024; }

    const int tid = threadIdx.x, lane = tid & 63, w = tid >> 6;
    const int wm = w >> 1, wn = w & 1;       // wave tile 64 x 64
    const int cc = lane & 15;
    const int sr = tid >> 3;                 // 0..31
    const int sc = (tid & 7) * 8;

    if (tid < 128) sld[tid] = s[m0 + tid];

    f32x4 acc[4][4] = {};

    // prologue: stage A0 (4 loads) then B0 (4 loads)
    #pragma unroll
    for (int i = 0; i < 4; ++i) {
        const int r = i * 32 + sr;
        const int cs = sc ^ ((r & 7) << 3);
        gload_lds16(xb + (size_t)(m0 + r) * 1024 + cs, (char*)As[0] + i * 4096 + w * 1024);
    }
    #pragma unroll
    for (int i = 0; i < 4; ++i) {
        const int r = i * 32 + sr;
        const int cs = sc ^ ((r & 7) << 3);
        gload_lds16(Bt + (size_t)(n0 + r) * 1024 + cs, (char*)Bs + i * 4096 + w * 1024);
    }

    for (int t = 0; t < 16; ++t) {
        if (t + 1 < 16) {
            const int k0 = (t + 1) * 64;
            char* ad = (char*)As[(t + 1) & 1];
            #pragma unroll
            for (int i = 0; i < 4; ++i) {
                const int r = i * 32 + sr;
                const int cs = sc ^ ((r & 7) << 3);
                gload_lds16(xb + (size_t)(m0 + r) * 1024 + k0 + cs, ad + i * 4096 + w * 1024);
            }
            asm volatile("s_waitcnt vmcnt(4)" ::: "memory");  // A[t],B[t] landed; A[t+1] flying
        } else {
            asm volatile("s_waitcnt vmcnt(0)" ::: "memory");
        }
        __builtin_amdgcn_s_barrier();

        const char* Ac = (const char*)As[t & 1];
        const char* Bc = (const char*)Bs;

        short8 af[4][2], bf[4][2];
        #pragma unroll
        for (int mf = 0; mf < 4; ++mf)
            #pragma unroll
            for (int ks = 0; ks < 2; ++ks) {
                const int r = wm * 64 + mf * 16 + cc;
                const int cb = (ks * 64 + ((lane >> 4) * 16)) ^ ((r & 7) << 4);
                af[mf][ks] = *reinterpret_cast<const short8*>(Ac + r * 128 + cb);
            }
        #pragma unroll
        for (int nf = 0; nf < 4; ++nf)
            #pragma unroll
            for (int ks = 0; ks < 2; ++ks) {
                const int r = wn * 64 + nf * 16 + cc;
                const int cb = (ks * 64 + ((lane >> 4) * 16)) ^ ((r & 7) << 4);
                bf[nf][ks] = *reinterpret_cast<const short8*>(Bc + r * 128 + cb);
            }
        #pragma unroll
        for (int ks = 0; ks < 2; ++ks)
            #pragma unroll
            for (int mf = 0; mf < 4; ++mf)
                #pragma unroll
                for (int nf = 0; nf < 4; ++nf)
                    acc[mf][nf] = __builtin_amdgcn_mfma_f32_16x16x32_bf16(af[mf][ks], bf[nf][ks], acc[mf][nf], 0, 0, 0);

        __builtin_amdgcn_s_barrier();   // all waves done reading As[t&1] / Bs

        if (t + 1 < 16) {               // stage B[t+1] into the single B buffer
            const int k0 = (t + 1) * 64;
            #pragma unroll
            for (int i = 0; i < 4; ++i) {
                const int r = i * 32 + sr;
                const int cs = sc ^ ((r & 7) << 3);
                gload_lds16(Bt + (size_t)(n0 + r) * 1024 + k0 + cs, (char*)Bs + i * 4096 + w * 1024);
            }
        }
    }

    if (bx < 16) {
        // rope epilogue; q additionally scaled by per-row s (f32). Head = 64-col span (wn half).
        const float2* tab = (bx < 8) ? tabq : tabk;
        unsigned short* dst = (bx < 8) ? qb : kb;
        const bool doscale = (bx < 8);
        #pragma unroll
        for (int mf = 0; mf < 4; ++mf)
            #pragma unroll
            for (int reg = 0; reg < 4; ++reg) {
                const int rloc = wm * 64 + mf * 16 + (lane >> 4) * 4 + reg;
                const int row = m0 + rloc;
                const int n = row & (N_ - 1);
                const float srow = doscale ? sld[rloc] : 1.0f;
                #pragma unroll
                for (int nf = 0; nf < 2; ++nf) {
                    const int d = nf * 16 + cc;
                    const float2 t1 = tab[n * 64 + d];
                    const float2 t2 = tab[n * 64 + 32 + d];
                    const float x1 = acc[mf][nf][reg] * srow;
                    const float x2 = acc[mf][nf + 2][reg] * srow;
                    const float o1 = x1 * t1.x - x2 * t1.y;
                    const float o2 = x2 * t2.x + x1 * t2.y;
                    const int col = n0 + wn * 64 + nf * 16 + cc;
                    dst[(size_t)row * 1024 + col] = f2bf(o1);
                    dst[(size_t)row * 1024 + col + 32] = f2bf(o2);
                }
            }
    } else {
        // V: store transposed into vt[bh*64+d][pos], within-64-tile key permutation:
        // key = mf*16 + g*4 + reg (bits mf1,mf0,g1,g0,r1,r0) ->
        // pos = mf1*32 + g1*16 + g0*8 + mf0*4 + reg   (reg contiguous -> 8B store)
        const int bb = m0 >> 11;                 // batch
        const int gg = lane >> 4;
        const int tb = (m0 & (N_ - 1)) + wm * 64;   // 64-aligned key-tile base
        #pragma unroll
        for (int mf = 0; mf < 4; ++mf) {
            const int npos = tb + (mf >> 1) * 32 + (gg >> 1) * 16 + (gg & 1) * 8 + (mf & 1) * 4;
            #pragma unroll
            for (int nf = 0; nf < 4; ++nf) {
                const int cv = n0 - 1024 + wn * 64 + nf * 16 + cc;   // 0..1023
                const int h = cv >> 6, d = cv & 63;
                uint2 u;
                u.x = cvt_pk_bf16(acc[mf][nf][0], acc[mf][nf][1]);
                u.y = cvt_pk_bf16(acc[mf][nf][2], acc[mf][nf][3]);
                *reinterpret_cast<uint2*>(vt + ((size_t)(bb * 16 + h) * 64 + d) * 2048 + npos) = u;
            }
        }
    }
}

// ---------------- output GEMM: C = att @ Wot^T + bo (f32 out), BN=64, XCD-affine, dbuf ----------------
__global__ __launch_bounds__(256) void gemm_o_kernel(const unsigned short* __restrict__ A,
                                                     const unsigned short* __restrict__ Bt,
                                                     const float* __restrict__ bias,
                                                     float* __restrict__ Cout) {
    __shared__ unsigned short As[2][128 * 64];
    __shared__ unsigned short Bs[2][64 * 64];
    const int bid = blockIdx.x;
    const int xcd = bid & 7;
    const int ii = bid >> 3;
    const int n0 = (xcd * 2 + (ii & 1)) * 64;
    const int m0 = (ii >> 1) * 128;
    const int tid = threadIdx.x, lane = tid & 63, w = tid >> 6;
    const int wm = w >> 1, wn = w & 1;
    const int cc = lane & 15;
    const int sr = tid >> 3;
    const int sc = (tid & 7) * 8;

    f32x4 acc[4][2] = {};

    #pragma unroll
    for (int i = 0; i < 4; ++i) {
        const int r = i * 32 + sr;
        const int cs = sc ^ ((r & 7) << 3);
        gload_lds16(A + (size_t)(m0 + r) * 1024 + cs, (char*)As[0] + i * 4096 + w * 1024);
        if (i < 2)
            gload_lds16(Bt + (size_t)(n0 + r) * 1024 + cs, (char*)Bs[0] + i * 4096 + w * 1024);
    }

    for (int t = 0; t < 16; ++t) {
        if (t + 1 < 16) {
            const int k0 = (t + 1) * 64;
            char* ad = (char*)As[(t + 1) & 1];
            char* bd = (char*)Bs[(t + 1) & 1];
            #pragma unroll
            for (int i = 0; i < 4; ++i) {
                const int r = i * 32 + sr;
                const int cs = sc ^ ((r & 7) << 3);
                gload_lds16(A + (size_t)(m0 + r) * 1024 + k0 + cs, ad + i * 4096 + w * 1024);
                if (i < 2)
                    gload_lds16(Bt + (size_t)(n0 + r) * 1024 + k0 + cs, bd + i * 4096 + w * 1024);
            }
            asm volatile("s_waitcnt vmcnt(6)" ::: "memory");
        } else {
            asm volatile("s_waitcnt vmcnt(0)" ::: "memory");
        }
        __builtin_amdgcn_s_barrier();

        const char* Ac = (const char*)As[t & 1];
        const char* Bc = (const char*)Bs[t & 1];

        short8 af[4][2], bf[2][2];
        #pragma unroll
        for (int mf = 0; mf < 4; ++mf)
            #pragma unroll
            for (int ks = 0; ks < 2; ++ks) {
                const int r = wm * 64 + mf * 16 + cc;
                const int cb = (ks * 64 + ((lane >> 4) * 16)) ^ ((r & 7) << 4);
                af[mf][ks] = *reinterpret_cast<const short8*>(Ac + r * 128 + cb);
            }
        #pragma unroll
        for (int nf = 0; nf < 2; ++nf)
            #pragma unroll
            for (int ks = 0; ks < 2; ++ks) {
                const int r = wn * 32 + nf * 16 + cc;
                const int cb = (ks * 64 + ((lane >> 4) * 16)) ^ ((r & 7) << 4);
                bf[nf][ks] = *reinterpret_cast<const short8*>(Bc + r * 128 + cb);
            }
        #pragma unroll
        for (int ks = 0; ks < 2; ++ks)
            #pragma unroll
            for (int mf = 0; mf < 4; ++mf)
                #pragma unroll
                for (int nf = 0; nf < 2; ++nf)
                    acc[mf][nf] = __builtin_amdgcn_mfma_f32_16x16x32_bf16(af[mf][ks], bf[nf][ks], acc[mf][nf], 0, 0, 0);

        __builtin_amdgcn_s_barrier();
    }

    float bb[2];
    #pragma unroll
    for (int nf = 0; nf < 2; ++nf) bb[nf] = bias[n0 + wn * 32 + nf * 16 + cc];
    #pragma unroll
    for (int mf = 0; mf < 4; ++mf)
        #pragma unroll
        for (int nf = 0; nf < 2; ++nf)
            #pragma unroll
            for (int reg = 0; reg < 4; ++reg) {
                const int row = m0 + wm * 64 + mf * 16 + (lane >> 4) * 4 + reg;
                const int col = n0 + wn * 32 + nf * 16 + cc;
                Cout[(size_t)row * 1024 + col] = acc[mf][nf][reg] + bb[nf];
            }
}

// ---------------- bf16 MFMA causal flash attention, split-KV, 24KB LDS, P fully in-register ----
// grid 1536. xcd=bid&7 (bh affinity). Balanced CU mapping: co-resident blocks (same u=rest&31,
// v=0..5) get one complementary pair from each work class -> per-CU work 65-67 units.
__global__ __launch_bounds__(256, 6) void attn_mfma_kernel(const unsigned short* __restrict__ q,
                                                           const unsigned short* __restrict__ kb,
                                                           const unsigned short* __restrict__ vt,
                                                           unsigned short* __restrict__ att,
                                                           unsigned short* __restrict__ pO,
                                                           float2* __restrict__ pml) {
    const int bid = blockIdx.x;
    const int xcd = bid & 7;
    const int rest = bid >> 3;          // 0..191
    const int v = rest >> 5;            // 0..5
    const int u = rest & 31;            // 0..31
    const int a = u >> 4;               // 0..1
    const int p = u & 15;               // 0..15
    const int bh = xcd * 4 + 2 * a + (v & 1);
    const int s = (v >> 1) * 16 + ((v & 1) ? (15 - p) : p);
    int qi, t0, t1, half;
    bool split;
    if (s < 16) {
        qi = s; t0 = 0; t1 = qi + 1; half = 0; split = false;
    } else {
        const int qs = s - 16;
        qi = 16 + (qs >> 1);
        half = qs & 1;
        const int hmid = (qi + 2) >> 1;
        t0 = half ? hmid : 0;
        t1 = half ? (qi + 1) : hmid;
        split = true;
    }
    const int b = bh >> 4, h = bh & 15;
    const int qb_ = qi * 64;
    const int tid = threadIdx.x;
    const int lane = tid & 63;
    const int w = tid >> 6;
    const int c = lane & 15;
    const int g = lane >> 4;

    __shared__ __align__(16) unsigned short Ks[2][64 * 64];   // [key][d] swizzled (dbuf, 16KB)
    __shared__ __align__(16) unsigned short Vs[64 * 64];      // [d][key-pos] swizzled (8KB)

    const int qrow = qb_ + w * 16 + c;
    short8 qf[2];
    {
        const unsigned short* qp = q + (size_t)(b * N_ + qrow) * 1024 + h * 64 + g * 8;
        qf[0] = *reinterpret_cast<const short8*>(qp);
        qf[1] = *reinterpret_cast<const short8*>(qp + 32);
    }

    float m = -1e30f, l = 0.f;
    f32x4 oacc[4] = {};

    const int sr = tid >> 3, sc = (tid & 7) * 8;
    const unsigned short* kbase = kb + (size_t)b * N_ * 1024 + h * 64;
    const unsigned short* vbase = vt + (size_t)bh * 64 * 2048;

    #pragma unroll
    for (int i = 0; i < 2; ++i) {
        const int r = i * 32 + sr;
        const int cs = sc ^ ((r & 7) << 3);
        gload_lds16(kbase + (size_t)(t0 * 64 + r) * 1024 + cs,
                    (char*)Ks[t0 & 1] + i * 4096 + w * 1024);
        gload_lds16(vbase + (size_t)r * 2048 + t0 * 64 + cs,
                    (char*)Vs + i * 4096 + w * 1024);
    }

    for (int t = t0; t < t1; ++t) {
        const int jb = t * 64;
        const int jn = jb + 64;
        if (t + 1 < t1) {
            char* kd = (char*)Ks[(t + 1) & 1];
            #pragma unroll
            for (int i = 0; i < 2; ++i) {
                const int r = i * 32 + sr;
                const int cs = sc ^ ((r & 7) << 3);
                gload_lds16(kbase + (size_t)(jn + r) * 1024 + cs, kd + i * 4096 + w * 1024);
            }
            asm volatile("s_waitcnt vmcnt(2)" ::: "memory");
        } else {
            asm volatile("s_waitcnt vmcnt(0)" ::: "memory");
        }
        __builtin_amdgcn_s_barrier();

        const char* Ksc = (const char*)Ks[t & 1];
        const char* Vsc = (const char*)Vs;

        f32x4 st[4];
        __builtin_amdgcn_s_setprio(1);
        #pragma unroll
        for (int ct = 0; ct < 4; ++ct) {
            const int key = ct * 16 + c;
            f32x4 acc = {0.f, 0.f, 0.f, 0.f};
            #pragma unroll
            for (int ks = 0; ks < 2; ++ks) {
                const int addr = (key * 128 + ks * 64 + g * 16) ^ ((key & 7) << 4);
                const short8 kf = *reinterpret_cast<const short8*>(Ksc + addr);
                acc = __builtin_amdgcn_mfma_f32_16x16x32_bf16(kf, qf[ks], acc, 0, 0, 0);
            }
            st[ct] = acc;
        }
        __builtin_amdgcn_s_setprio(0);

        float mx = -1e30f;
        if (jb + 63 > qrow) {
            #pragma unroll
            for (int ct = 0; ct < 4; ++ct)
                #pragma unroll
                for (int reg = 0; reg < 4; ++reg) {
                    const int key = jb + ct * 16 + g * 4 + reg;
                    const float sv = (key <= qrow) ? st[ct][reg] : -1e30f;
                    st[ct][reg] = sv;
                    mx = fmaxf(mx, sv);
                }
        } else {
            #pragma unroll
            for (int ct = 0; ct < 4; ++ct)
                mx = fmaxf(mx, fmaxf(fmaxf(st[ct][0], st[ct][1]),
                                     fmaxf(st[ct][2], st[ct][3])));
        }
        mx = fmaxf(mx, __shfl_xor(mx, 16, 64));
        mx = fmaxf(mx, __shfl_xor(mx, 32, 64));
        if (!__all(mx <= m + 8.0f)) {
            const float mn = fmaxf(m, mx);
            const float corr = exp2_fast(m - mn);
            l *= corr;
            m = mn;
            #pragma unroll
            for (int dt = 0; dt < 4; ++dt) {
                oacc[dt][0] *= corr; oacc[dt][1] *= corr;
                oacc[dt][2] *= corr; oacc[dt][3] *= corr;
            }
        }
        float rs = 0.f;
        #pragma unroll
        for (int ct = 0; ct < 4; ++ct)
            #pragma unroll
            for (int reg = 0; reg < 4; ++reg) {
                const float p2 = exp2_fast(st[ct][reg] - m);
                st[ct][reg] = p2;
                rs += p2;
            }
        rs += __shfl_xor(rs, 16, 64);
        rs += __shfl_xor(rs, 32, 64);
        l += rs;

        uint4v pv0, pv1;
        pv0[0] = cvt_pk_bf16(st[0][0], st[0][1]);
        pv0[1] = cvt_pk_bf16(st[0][2], st[0][3]);
        pv0[2] = cvt_pk_bf16(st[1][0], st[1][1]);
        pv0[3] = cvt_pk_bf16(st[1][2], st[1][3]);
        pv1[0] = cvt_pk_bf16(st[2][0], st[2][1]);
        pv1[1] = cvt_pk_bf16(st[2][2], st[2][3]);
        pv1[2] = cvt_pk_bf16(st[3][0], st[3][1]);
        pv1[3] = cvt_pk_bf16(st[3][2], st[3][3]);
        const short8 pf0 = *reinterpret_cast<const short8*>(&pv0);
        const short8 pf1 = *reinterpret_cast<const short8*>(&pv1);

        __builtin_amdgcn_s_setprio(1);
        #pragma unroll
        for (int dt = 0; dt < 4; ++dt) {
            const int vd = dt * 16 + c;
            {
                const int addr = (vd * 128 + 0 * 64 + g * 16) ^ ((vd & 7) << 4);
                const short8 vf = *reinterpret_cast<const short8*>(Vsc + addr);
                oacc[dt] = __builtin_amdgcn_mfma_f32_16x16x32_bf16(vf, pf0, oacc[dt], 0, 0, 0);
            }
            {
                const int addr = (vd * 128 + 1 * 64 + g * 16) ^ ((vd & 7) << 4);
                const short8 vf = *reinterpret_cast<const short8*>(Vsc + addr);
                oacc[dt] = __builtin_amdgcn_mfma_f32_16x16x32_bf16(vf, pf1, oacc[dt], 0, 0, 0);
            }
        }
        __builtin_amdgcn_s_setprio(0);

        __builtin_amdgcn_s_barrier();

        if (t + 1 < t1) {
            #pragma unroll
            for (int i = 0; i < 2; ++i) {
                const int r = i * 32 + sr;
                const int cs = sc ^ ((r & 7) << 3);
                gload_lds16(vbase + (size_t)r * 2048 + jn + cs, (char*)Vs + i * 4096 + w * 1024);
            }
        }
    }

    if (!split) {
        const float inv = 1.0f / l;
        unsigned short* orow = att + (size_t)(b * N_ + qrow) * 1024 + h * 64;
        #pragma unroll
        for (int dt = 0; dt < 4; ++dt) {
            #pragma unroll
            for (int rp = 0; rp < 2; ++rp) {
                const unsigned uu = cvt_pk_bf16(oacc[dt][2 * rp] * inv,
                                                oacc[dt][2 * rp + 1] * inv);
                *reinterpret_cast<unsigned*>(orow + dt * 16 + g * 4 + rp * 2) = uu;
            }
        }
    } else {
        const int slot = (bh * 16 + (qi - 16)) * 2 + half;
        const int rloc = w * 16 + c;
        pml[slot * 64 + rloc] = make_float2(m, l);
        unsigned short* prow = pO + (size_t)slot * 4096 + rloc * 64;
        #pragma unroll
        for (int dt = 0; dt < 4; ++dt) {
            #pragma unroll
            for (int rp = 0; rp < 2; ++rp) {
                const unsigned uu = cvt_pk_bf16(oacc[dt][2 * rp], oacc[dt][2 * rp + 1]);
                *reinterpret_cast<unsigned*>(prow + dt * 16 + g * 4 + rp * 2) = uu;
            }
        }
    }
}

// ---------------- merge split-KV partials ----------------
__global__ __launch_bounds__(256) void attn_merge_kernel(const unsigned short* __restrict__ pO,
                                                         const float2* __restrict__ pml,
                                                         unsigned short* __restrict__ att) {
    const int blk = blockIdx.x;        // 0..511 = bh*16 + qt
    const int bh = blk >> 4;
    const int qt = blk & 15;
    const int qi = 16 + qt;
    const int b = bh >> 4, h = bh & 15;
    const int tid = threadIdx.x;
    const int row = tid >> 2;
    const int d0 = (tid & 3) * 16;
    const int slot0 = (bh * 16 + qt) * 2;
    const float2 ml0 = pml[slot0 * 64 + row];
    const float2 ml1 = pml[(slot0 + 1) * 64 + row];
    const float M = fmaxf(ml0.x, ml1.x);
    const float w0 = exp2_fast(ml0.x - M);
    const float w1 = exp2_fast(ml1.x - M);
    const float invL = 1.0f / (ml0.y * w0 + ml1.y * w1);
    const unsigned short* p0 = pO + (size_t)slot0 * 4096 + row * 64 + d0;
    const unsigned short* p1 = p0 + 4096;
    const int qrow = qi * 64 + row;
    unsigned short* orow = att + (size_t)(b * N_ + qrow) * 1024 + h * 64 + d0;
    #pragma unroll
    for (int j = 0; j < 16; j += 2) {
        const float a0 = (bf2f(p0[j]) * w0 + bf2f(p1[j]) * w1) * invL;
        const float a1 = (bf2f(p0[j + 1]) * w0 + bf2f(p1[j + 1]) * w1) * invL;
        *reinterpret_cast<unsigned*>(orow + j) = cvt_pk_bf16(a0, a1);
    }
}

extern "C" void kernel_launch(void* const* d_in, const int* in_sizes, int n_in,
                              void* d_out, int out_size, void* d_ws, size_t ws_size,
                              hipStream_t stream) {
    const float* x     = (const float*)d_in[0];
    const float* pos   = (const float*)d_in[1];
    const float* gamma = (const float*)d_in[2];
    const float* Wq    = (const float*)d_in[3];
    const float* Wkv   = (const float*)d_in[4];
    const float* Wo    = (const float*)d_in[5];
    const float* bo    = (const float*)d_in[6];
    float* out = (float*)d_out;
    char* ws = (char*)d_ws;

    const size_t MB = 1024 * 1024;
    unsigned short* kb   = (unsigned short*)(ws);             // 8 MB roped K
    unsigned short* qb   = (unsigned short*)(ws + 16 * MB);   // 8 MB roped+scaled Q
    unsigned short* att  = (unsigned short*)(ws + 24 * MB);   // 8 MB attention output
    unsigned short* xb   = (unsigned short*)(ws + 32 * MB);   // 8 MB bf16 x (dead after qkv)
    unsigned short* Wqt  = (unsigned short*)(ws + 40 * MB);   // 2 MB
    unsigned short* Wkvt = (unsigned short*)(ws + 42 * MB);   // 4 MB
    unsigned short* Wot  = (unsigned short*)(ws + 46 * MB);   // 2 MB
    unsigned short* vt   = (unsigned short*)(ws + 48 * MB);   // 8 MB V^T [bh][d][pos]
    float2* tabq         = (float2*)(ws + 56 * MB);           // 1 MB
    float2* tabk         = (float2*)(ws + 57 * MB);           // 1 MB
    float* sv            = (float*)(ws + 58 * MB);            // 16 KB
    unsigned short* pO   = (unsigned short*)(ws + 32 * MB);   // 8.4 MB (overlay, after qkv)
    float2* pml          = (float2*)(ws + 40 * MB + 512 * 1024);  // 512 KB

    prologue_kernel<<<8704, 256, 0, stream>>>(
        x, pos, gamma, Wq, Wkv, Wo, xb, sv, tabq, tabk, Wqt, Wkvt, Wot);

    gemm_qkv_kernel<<<768, 256, 0, stream>>>(
        xb, Wqt, Wkvt, sv, qb, kb, vt, tabq, tabk);

    attn_mfma_kernel<<<1536, 256, 0, stream>>>(qb, kb, vt, att, pO, pml);
    attn_merge_kernel<<<512, 256, 0, stream>>>(pO, pml, att);

    gemm_o_kernel<<<512, 256, 0, stream>>>(att, Wot, bo, out);
}

// Round 22
// 100.636 us; speedup vs baseline: 1.2149x; 1.0049x over previous
//
#include <hip/hip_runtime.h>
#include <cmath>

#define B_ 2
#define N_ 2048
#define D_ 1024
#define H_ 16

typedef __attribute__((ext_vector_type(8))) short short8;
typedef __attribute__((ext_vector_type(4))) float f32x4;
typedef __attribute__((ext_vector_type(4))) unsigned short u16x4;
typedef __attribute__((ext_vector_type(4))) unsigned int uint4v;

__device__ __forceinline__ unsigned short f2bf(float f) {
    union { float f; unsigned u; } x;
    x.f = f;
    unsigned r = x.u + 0x7FFFu + ((x.u >> 16) & 1u);
    return (unsigned short)(r >> 16);
}
__device__ __forceinline__ float bf2f(unsigned short u) {
    union { unsigned u; float f; } x;
    x.u = ((unsigned)u) << 16;
    return x.f;
}
__device__ __forceinline__ unsigned cvt_pk_bf16(float lo, float hi) {
    unsigned r;
    asm("v_cvt_pk_bf16_f32 %0, %1, %2" : "=v"(r) : "v"(lo), "v"(hi));
    return r;
}
__device__ __forceinline__ float exp2_fast(float x) {
    float r;
    asm("v_exp_f32 %0, %1" : "=v"(r) : "v"(x));
    return r;
}
__device__ __forceinline__ float max3f(float a, float b, float c) {
    return fmaxf(fmaxf(a, b), c);   // clang fuses to v_max3_f32
}
__device__ __forceinline__ void gload_lds16(const void* g, void* l) {
    __builtin_amdgcn_global_load_lds((const __attribute__((address_space(1))) unsigned*)g,
                                     (__attribute__((address_space(3))) unsigned*)l,
                                     16, 0, 0);
}

// ---------------- fused prologue: convT (bid<4096) | rmsnorm (4096..8191) | freqtab (8192..8703) ----
__global__ __launch_bounds__(256) void prologue_kernel(const float* __restrict__ x,
                                                       const float* __restrict__ pos,
                                                       const float* __restrict__ gamma,
                                                       const float* __restrict__ Wq,
                                                       const float* __restrict__ Wkv,
                                                       const float* __restrict__ Wo,
                                                       unsigned short* __restrict__ xb,
                                                       float* __restrict__ s,
                                                       float2* __restrict__ tabq,
                                                       float2* __restrict__ tabk,
                                                       unsigned short* __restrict__ Wqt,
                                                       unsigned short* __restrict__ Wkvt,
                                                       unsigned short* __restrict__ Wot) {
    __shared__ float tile[32][33];
    __shared__ float wss[4];
    const int bid = blockIdx.x;
    if (bid < 4096) {
        const int bx = bid & 127;
        const int k0 = (bid >> 7) * 32;
        const float* W;
        unsigned short* Wt;
        int Nm, n0;
        bool gmul = false;
        if (bx < 32)       { W = Wq;  Wt = Wqt;  Nm = 1024; n0 = bx * 32; gmul = true; }
        else if (bx < 96)  { W = Wkv; Wt = Wkvt; Nm = 2048; n0 = (bx - 32) * 32; }
        else               { W = Wo;  Wt = Wot;  Nm = 1024; n0 = (bx - 96) * 32; }
        const int r = threadIdx.x >> 3, c4 = (threadIdx.x & 7) * 4;
        const float4 ld = *reinterpret_cast<const float4*>(W + (size_t)(k0 + r) * Nm + n0 + c4);
        tile[r][c4 + 0] = ld.x; tile[r][c4 + 1] = ld.y;
        tile[r][c4 + 2] = ld.z; tile[r][c4 + 3] = ld.w;
        __syncthreads();
        u16x4 o;
        #pragma unroll
        for (int j = 0; j < 4; ++j) {
            float v = tile[c4 + j][r];
            if (gmul) v *= gamma[k0 + c4 + j];
            o[j] = f2bf(v);
        }
        *reinterpret_cast<u16x4*>(Wt + (size_t)(n0 + r) * 1024 + k0 + c4) = o;
    } else if (bid < 8192) {
        const int row = bid - 4096;
        const float4 v = reinterpret_cast<const float4*>(x + (size_t)row * D_)[threadIdx.x];
        float ss = v.x * v.x + v.y * v.y + v.z * v.z + v.w * v.w;
        #pragma unroll
        for (int off = 32; off; off >>= 1) ss += __shfl_xor(ss, off, 64);
        if ((threadIdx.x & 63) == 0) wss[threadIdx.x >> 6] = ss;
        __syncthreads();
        const float tot = wss[0] + wss[1] + wss[2] + wss[3];
        const float inv = 1.0f / fmaxf(sqrtf(tot * (1.0f / D_)), 1e-8f);
        if (threadIdx.x == 0) s[row] = inv;
        u16x4 ox;
        ox[0] = f2bf(v.x); ox[1] = f2bf(v.y); ox[2] = f2bf(v.z); ox[3] = f2bf(v.w);
        *reinterpret_cast<u16x4*>(xb + (size_t)row * D_ + threadIdx.x * 4) = ox;
    } else {
        const int idx = (bid - 8192) * 256 + threadIdx.x;
        const float f = pos[idx];
        const float cc = cosf(f), ssn = sinf(f);
        const float sq = 0.125f * 1.4426950408889634f;
        tabq[idx] = make_float2(sq * cc, sq * ssn);
        tabk[idx] = make_float2(cc, ssn);
    }
}

// ---------------- merged q + kv GEMM: BM=128, BN=128, BK=64, A dbuf + B single, 48.5KB LDS -----
__global__ __launch_bounds__(256, 3) void gemm_qkv_kernel(const unsigned short* __restrict__ xb,
                                                          const unsigned short* __restrict__ Wqt,
                                                          const unsigned short* __restrict__ Wkvt,
                                                          const float* __restrict__ s,
                                                          unsigned short* __restrict__ qb,
                                                          unsigned short* __restrict__ kb,
                                                          unsigned short* __restrict__ vt,
                                                          const float2* __restrict__ tabq,
                                                          const float2* __restrict__ tabk) {
    __shared__ unsigned short As[2][128 * 64];   // 16KB each
    __shared__ unsigned short Bs[128 * 64];      // 16KB single
    __shared__ float sld[128];
    const int bid = blockIdx.x;
    const int xcd = bid & 7;
    const int ii = bid >> 3;                 // 0..95
    const int bx = xcd * 3 + (ii % 3);       // 0..23
    const int m0 = (ii / 3) * 128;           // 0..3968

    const unsigned short* Bt;
    int n0;
    if (bx < 8)       { Bt = Wqt;  n0 = bx * 128; }
    else if (bx < 16) { Bt = Wkvt; n0 = (bx - 8) * 128; }
    else              { Bt = Wkvt; n0 = (bx - 16) * 128 + 1024; }

    const int tid = threadIdx.x, lane = tid & 63, w = tid >> 6;
    const int wm = w >> 1, wn = w & 1;       // wave tile 64 x 64
    const int cc = lane & 15;
    const int sr = tid >> 3;                 // 0..31
    const int sc = (tid & 7) * 8;

    if (tid < 128) sld[tid] = s[m0 + tid];

    f32x4 acc[4][4] = {};

    #pragma unroll
    for (int i = 0; i < 4; ++i) {
        const int r = i * 32 + sr;
        const int cs = sc ^ ((r & 7) << 3);
        gload_lds16(xb + (size_t)(m0 + r) * 1024 + cs, (char*)As[0] + i * 4096 + w * 1024);
    }
    #pragma unroll
    for (int i = 0; i < 4; ++i) {
        const int r = i * 32 + sr;
        const int cs = sc ^ ((r & 7) << 3);
        gload_lds16(Bt + (size_t)(n0 + r) * 1024 + cs, (char*)Bs + i * 4096 + w * 1024);
    }

    for (int t = 0; t < 16; ++t) {
        if (t + 1 < 16) {
            const int k0 = (t + 1) * 64;
            char* ad = (char*)As[(t + 1) & 1];
            #pragma unroll
            for (int i = 0; i < 4; ++i) {
                const int r = i * 32 + sr;
                const int cs = sc ^ ((r & 7) << 3);
                gload_lds16(xb + (size_t)(m0 + r) * 1024 + k0 + cs, ad + i * 4096 + w * 1024);
            }
            asm volatile("s_waitcnt vmcnt(4)" ::: "memory");  // A[t],B[t] landed; A[t+1] flying
        } else {
            asm volatile("s_waitcnt vmcnt(0)" ::: "memory");
        }
        __builtin_amdgcn_s_barrier();

        const char* Ac = (const char*)As[t & 1];
        const char* Bc = (const char*)Bs;

        short8 af[4][2], bf[4][2];
        #pragma unroll
        for (int mf = 0; mf < 4; ++mf)
            #pragma unroll
            for (int ks = 0; ks < 2; ++ks) {
                const int r = wm * 64 + mf * 16 + cc;
                const int cb = (ks * 64 + ((lane >> 4) * 16)) ^ ((r & 7) << 4);
                af[mf][ks] = *reinterpret_cast<const short8*>(Ac + r * 128 + cb);
            }
        #pragma unroll
        for (int nf = 0; nf < 4; ++nf)
            #pragma unroll
            for (int ks = 0; ks < 2; ++ks) {
                const int r = wn * 64 + nf * 16 + cc;
                const int cb = (ks * 64 + ((lane >> 4) * 16)) ^ ((r & 7) << 4);
                bf[nf][ks] = *reinterpret_cast<const short8*>(Bc + r * 128 + cb);
            }
        #pragma unroll
        for (int ks = 0; ks < 2; ++ks)
            #pragma unroll
            for (int mf = 0; mf < 4; ++mf)
                #pragma unroll
                for (int nf = 0; nf < 4; ++nf)
                    acc[mf][nf] = __builtin_amdgcn_mfma_f32_16x16x32_bf16(af[mf][ks], bf[nf][ks], acc[mf][nf], 0, 0, 0);

        __builtin_amdgcn_s_barrier();   // all waves done reading As[t&1] / Bs

        if (t + 1 < 16) {
            const int k0 = (t + 1) * 64;
            #pragma unroll
            for (int i = 0; i < 4; ++i) {
                const int r = i * 32 + sr;
                const int cs = sc ^ ((r & 7) << 3);
                gload_lds16(Bt + (size_t)(n0 + r) * 1024 + k0 + cs, (char*)Bs + i * 4096 + w * 1024);
            }
        }
    }

    if (bx < 16) {
        const float2* tab = (bx < 8) ? tabq : tabk;
        unsigned short* dst = (bx < 8) ? qb : kb;
        const bool doscale = (bx < 8);
        #pragma unroll
        for (int mf = 0; mf < 4; ++mf)
            #pragma unroll
            for (int reg = 0; reg < 4; ++reg) {
                const int rloc = wm * 64 + mf * 16 + (lane >> 4) * 4 + reg;
                const int row = m0 + rloc;
                const int n = row & (N_ - 1);
                const float srow = doscale ? sld[rloc] : 1.0f;
                #pragma unroll
                for (int nf = 0; nf < 2; ++nf) {
                    const int d = nf * 16 + cc;
                    const float2 t1 = tab[n * 64 + d];
                    const float2 t2 = tab[n * 64 + 32 + d];
                    const float x1 = acc[mf][nf][reg] * srow;
                    const float x2 = acc[mf][nf + 2][reg] * srow;
                    const float o1 = x1 * t1.x - x2 * t1.y;
                    const float o2 = x2 * t2.x + x1 * t2.y;
                    const int col = n0 + wn * 64 + nf * 16 + cc;
                    dst[(size_t)row * 1024 + col] = f2bf(o1);
                    dst[(size_t)row * 1024 + col + 32] = f2bf(o2);
                }
            }
    } else {
        // V: store transposed into vt[bh*64+d][pos], within-64-tile key permutation:
        // key = mf*16 + g*4 + reg -> pos = mf1*32 + g1*16 + g0*8 + mf0*4 + reg
        const int bb = m0 >> 11;
        const int gg = lane >> 4;
        const int tb = (m0 & (N_ - 1)) + wm * 64;
        #pragma unroll
        for (int mf = 0; mf < 4; ++mf) {
            const int npos = tb + (mf >> 1) * 32 + (gg >> 1) * 16 + (gg & 1) * 8 + (mf & 1) * 4;
            #pragma unroll
            for (int nf = 0; nf < 4; ++nf) {
                const int cv = n0 - 1024 + wn * 64 + nf * 16 + cc;
                const int h = cv >> 6, d = cv & 63;
                uint2 u;
                u.x = cvt_pk_bf16(acc[mf][nf][0], acc[mf][nf][1]);
                u.y = cvt_pk_bf16(acc[mf][nf][2], acc[mf][nf][3]);
                *reinterpret_cast<uint2*>(vt + ((size_t)(bb * 16 + h) * 64 + d) * 2048 + npos) = u;
            }
        }
    }
}

// ---------------- output GEMM: C = att @ Wot^T + bo (f32 out), BN=64, XCD-affine, dbuf ----------------
__global__ __launch_bounds__(256) void gemm_o_kernel(const unsigned short* __restrict__ A,
                                                     const unsigned short* __restrict__ Bt,
                                                     const float* __restrict__ bias,
                                                     float* __restrict__ Cout) {
    __shared__ unsigned short As[2][128 * 64];
    __shared__ unsigned short Bs[2][64 * 64];
    const int bid = blockIdx.x;
    const int xcd = bid & 7;
    const int ii = bid >> 3;
    const int n0 = (xcd * 2 + (ii & 1)) * 64;
    const int m0 = (ii >> 1) * 128;
    const int tid = threadIdx.x, lane = tid & 63, w = tid >> 6;
    const int wm = w >> 1, wn = w & 1;
    const int cc = lane & 15;
    const int sr = tid >> 3;
    const int sc = (tid & 7) * 8;

    f32x4 acc[4][2] = {};

    #pragma unroll
    for (int i = 0; i < 4; ++i) {
        const int r = i * 32 + sr;
        const int cs = sc ^ ((r & 7) << 3);
        gload_lds16(A + (size_t)(m0 + r) * 1024 + cs, (char*)As[0] + i * 4096 + w * 1024);
        if (i < 2)
            gload_lds16(Bt + (size_t)(n0 + r) * 1024 + cs, (char*)Bs[0] + i * 4096 + w * 1024);
    }

    for (int t = 0; t < 16; ++t) {
        if (t + 1 < 16) {
            const int k0 = (t + 1) * 64;
            char* ad = (char*)As[(t + 1) & 1];
            char* bd = (char*)Bs[(t + 1) & 1];
            #pragma unroll
            for (int i = 0; i < 4; ++i) {
                const int r = i * 32 + sr;
                const int cs = sc ^ ((r & 7) << 3);
                gload_lds16(A + (size_t)(m0 + r) * 1024 + k0 + cs, ad + i * 4096 + w * 1024);
                if (i < 2)
                    gload_lds16(Bt + (size_t)(n0 + r) * 1024 + k0 + cs, bd + i * 4096 + w * 1024);
            }
            asm volatile("s_waitcnt vmcnt(6)" ::: "memory");
        } else {
            asm volatile("s_waitcnt vmcnt(0)" ::: "memory");
        }
        __builtin_amdgcn_s_barrier();

        const char* Ac = (const char*)As[t & 1];
        const char* Bc = (const char*)Bs[t & 1];

        short8 af[4][2], bf[2][2];
        #pragma unroll
        for (int mf = 0; mf < 4; ++mf)
            #pragma unroll
            for (int ks = 0; ks < 2; ++ks) {
                const int r = wm * 64 + mf * 16 + cc;
                const int cb = (ks * 64 + ((lane >> 4) * 16)) ^ ((r & 7) << 4);
                af[mf][ks] = *reinterpret_cast<const short8*>(Ac + r * 128 + cb);
            }
        #pragma unroll
        for (int nf = 0; nf < 2; ++nf)
            #pragma unroll
            for (int ks = 0; ks < 2; ++ks) {
                const int r = wn * 32 + nf * 16 + cc;
                const int cb = (ks * 64 + ((lane >> 4) * 16)) ^ ((r & 7) << 4);
                bf[nf][ks] = *reinterpret_cast<const short8*>(Bc + r * 128 + cb);
            }
        #pragma unroll
        for (int ks = 0; ks < 2; ++ks)
            #pragma unroll
            for (int mf = 0; mf < 4; ++mf)
                #pragma unroll
                for (int nf = 0; nf < 2; ++nf)
                    acc[mf][nf] = __builtin_amdgcn_mfma_f32_16x16x32_bf16(af[mf][ks], bf[nf][ks], acc[mf][nf], 0, 0, 0);

        __builtin_amdgcn_s_barrier();
    }

    float bb[2];
    #pragma unroll
    for (int nf = 0; nf < 2; ++nf) bb[nf] = bias[n0 + wn * 32 + nf * 16 + cc];
    #pragma unroll
    for (int mf = 0; mf < 4; ++mf)
        #pragma unroll
        for (int nf = 0; nf < 2; ++nf)
            #pragma unroll
            for (int reg = 0; reg < 4; ++reg) {
                const int row = m0 + wm * 64 + mf * 16 + (lane >> 4) * 4 + reg;
                const int col = n0 + wn * 32 + nf * 16 + cc;
                Cout[(size_t)row * 1024 + col] = acc[mf][nf][reg] + bb[nf];
            }
}

// ---------------- bf16 MFMA causal flash attention, split-KV, 24KB LDS, P fully in-register ----
// grid 1536. xcd=bid&7 (bh affinity). Balanced CU mapping (65-67 tile-units/CU).
// Softmax: v_max3 row-max tree + pairwise-tree sum (T17).
__global__ __launch_bounds__(256, 6) void attn_mfma_kernel(const unsigned short* __restrict__ q,
                                                           const unsigned short* __restrict__ kb,
                                                           const unsigned short* __restrict__ vt,
                                                           unsigned short* __restrict__ att,
                                                           unsigned short* __restrict__ pO,
                                                           float2* __restrict__ pml) {
    const int bid = blockIdx.x;
    const int xcd = bid & 7;
    const int rest = bid >> 3;          // 0..191
    const int v = rest >> 5;            // 0..5
    const int u = rest & 31;            // 0..31
    const int a = u >> 4;               // 0..1
    const int p = u & 15;               // 0..15
    const int bh = xcd * 4 + 2 * a + (v & 1);
    const int s = (v >> 1) * 16 + ((v & 1) ? (15 - p) : p);
    int qi, t0, t1, half;
    bool split;
    if (s < 16) {
        qi = s; t0 = 0; t1 = qi + 1; half = 0; split = false;
    } else {
        const int qs = s - 16;
        qi = 16 + (qs >> 1);
        half = qs & 1;
        const int hmid = (qi + 2) >> 1;
        t0 = half ? hmid : 0;
        t1 = half ? (qi + 1) : hmid;
        split = true;
    }
    const int b = bh >> 4, h = bh & 15;
    const int qb_ = qi * 64;
    const int tid = threadIdx.x;
    const int lane = tid & 63;
    const int w = tid >> 6;
    const int c = lane & 15;
    const int g = lane >> 4;

    __shared__ __align__(16) unsigned short Ks[2][64 * 64];   // [key][d] swizzled (dbuf, 16KB)
    __shared__ __align__(16) unsigned short Vs[64 * 64];      // [d][key-pos] swizzled (8KB)

    const int qrow = qb_ + w * 16 + c;
    short8 qf[2];
    {
        const unsigned short* qp = q + (size_t)(b * N_ + qrow) * 1024 + h * 64 + g * 8;
        qf[0] = *reinterpret_cast<const short8*>(qp);
        qf[1] = *reinterpret_cast<const short8*>(qp + 32);
    }

    float m = -1e30f, l = 0.f;
    f32x4 oacc[4] = {};

    const int sr = tid >> 3, sc = (tid & 7) * 8;
    const unsigned short* kbase = kb + (size_t)b * N_ * 1024 + h * 64;
    const unsigned short* vbase = vt + (size_t)bh * 64 * 2048;

    #pragma unroll
    for (int i = 0; i < 2; ++i) {
        const int r = i * 32 + sr;
        const int cs = sc ^ ((r & 7) << 3);
        gload_lds16(kbase + (size_t)(t0 * 64 + r) * 1024 + cs,
                    (char*)Ks[t0 & 1] + i * 4096 + w * 1024);
        gload_lds16(vbase + (size_t)r * 2048 + t0 * 64 + cs,
                    (char*)Vs + i * 4096 + w * 1024);
    }

    for (int t = t0; t < t1; ++t) {
        const int jb = t * 64;
        const int jn = jb + 64;
        if (t + 1 < t1) {
            char* kd = (char*)Ks[(t + 1) & 1];
            #pragma unroll
            for (int i = 0; i < 2; ++i) {
                const int r = i * 32 + sr;
                const int cs = sc ^ ((r & 7) << 3);
                gload_lds16(kbase + (size_t)(jn + r) * 1024 + cs, kd + i * 4096 + w * 1024);
            }
            asm volatile("s_waitcnt vmcnt(2)" ::: "memory");
        } else {
            asm volatile("s_waitcnt vmcnt(0)" ::: "memory");
        }
        __builtin_amdgcn_s_barrier();

        const char* Ksc = (const char*)Ks[t & 1];
        const char* Vsc = (const char*)Vs;

        f32x4 st[4];
        __builtin_amdgcn_s_setprio(1);
        #pragma unroll
        for (int ct = 0; ct < 4; ++ct) {
            const int key = ct * 16 + c;
            f32x4 acc = {0.f, 0.f, 0.f, 0.f};
            #pragma unroll
            for (int ks = 0; ks < 2; ++ks) {
                const int addr = (key * 128 + ks * 64 + g * 16) ^ ((key & 7) << 4);
                const short8 kf = *reinterpret_cast<const short8*>(Ksc + addr);
                acc = __builtin_amdgcn_mfma_f32_16x16x32_bf16(kf, qf[ks], acc, 0, 0, 0);
            }
            st[ct] = acc;
        }
        __builtin_amdgcn_s_setprio(0);

        // exp2-domain online softmax with defer-max; v_max3 trees
        float mx;
        if (jb + 63 > qrow) {
            #pragma unroll
            for (int ct = 0; ct < 4; ++ct)
                #pragma unroll
                for (int reg = 0; reg < 4; ++reg) {
                    const int key = jb + ct * 16 + g * 4 + reg;
                    st[ct][reg] = (key <= qrow) ? st[ct][reg] : -1e30f;
                }
        }
        {
            const float t0m = max3f(st[0][0], st[0][1], st[0][2]);
            const float t1m = max3f(st[0][3], st[1][0], st[1][1]);
            const float t2m = max3f(st[1][2], st[1][3], st[2][0]);
            const float t3m = max3f(st[2][1], st[2][2], st[2][3]);
            const float t4m = max3f(st[3][0], st[3][1], st[3][2]);
            const float t5m = max3f(t0m, t1m, st[3][3]);
            const float t6m = max3f(t2m, t3m, t4m);
            mx = fmaxf(t5m, t6m);
        }
        mx = fmaxf(mx, __shfl_xor(mx, 16, 64));
        mx = fmaxf(mx, __shfl_xor(mx, 32, 64));
        if (!__all(mx <= m + 8.0f)) {
            const float mn = fmaxf(m, mx);
            const float corr = exp2_fast(m - mn);
            l *= corr;
            m = mn;
            #pragma unroll
            for (int dt = 0; dt < 4; ++dt) {
                oacc[dt][0] *= corr; oacc[dt][1] *= corr;
                oacc[dt][2] *= corr; oacc[dt][3] *= corr;
            }
        }
        float prt[4];
        #pragma unroll
        for (int ct = 0; ct < 4; ++ct) {
            float p0 = exp2_fast(st[ct][0] - m);
            float p1 = exp2_fast(st[ct][1] - m);
            float p2 = exp2_fast(st[ct][2] - m);
            float p3 = exp2_fast(st[ct][3] - m);
            st[ct][0] = p0; st[ct][1] = p1; st[ct][2] = p2; st[ct][3] = p3;
            prt[ct] = (p0 + p1) + (p2 + p3);
        }
        float rs = (prt[0] + prt[1]) + (prt[2] + prt[3]);
        rs += __shfl_xor(rs, 16, 64);
        rs += __shfl_xor(rs, 32, 64);
        l += rs;

        uint4v pv0, pv1;
        pv0[0] = cvt_pk_bf16(st[0][0], st[0][1]);
        pv0[1] = cvt_pk_bf16(st[0][2], st[0][3]);
        pv0[2] = cvt_pk_bf16(st[1][0], st[1][1]);
        pv0[3] = cvt_pk_bf16(st[1][2], st[1][3]);
        pv1[0] = cvt_pk_bf16(st[2][0], st[2][1]);
        pv1[1] = cvt_pk_bf16(st[2][2], st[2][3]);
        pv1[2] = cvt_pk_bf16(st[3][0], st[3][1]);
        pv1[3] = cvt_pk_bf16(st[3][2], st[3][3]);
        const short8 pf0 = *reinterpret_cast<const short8*>(&pv0);
        const short8 pf1 = *reinterpret_cast<const short8*>(&pv1);

        __builtin_amdgcn_s_setprio(1);
        #pragma unroll
        for (int dt = 0; dt < 4; ++dt) {
            const int vd = dt * 16 + c;
            {
                const int addr = (vd * 128 + 0 * 64 + g * 16) ^ ((vd & 7) << 4);
                const short8 vf = *reinterpret_cast<const short8*>(Vsc + addr);
                oacc[dt] = __builtin_amdgcn_mfma_f32_16x16x32_bf16(vf, pf0, oacc[dt], 0, 0, 0);
            }
            {
                const int addr = (vd * 128 + 1 * 64 + g * 16) ^ ((vd & 7) << 4);
                const short8 vf = *reinterpret_cast<const short8*>(Vsc + addr);
                oacc[dt] = __builtin_amdgcn_mfma_f32_16x16x32_bf16(vf, pf1, oacc[dt], 0, 0, 0);
            }
        }
        __builtin_amdgcn_s_setprio(0);

        __builtin_amdgcn_s_barrier();

        if (t + 1 < t1) {
            #pragma unroll
            for (int i = 0; i < 2; ++i) {
                const int r = i * 32 + sr;
                const int cs = sc ^ ((r & 7) << 3);
                gload_lds16(vbase + (size_t)r * 2048 + jn + cs, (char*)Vs + i * 4096 + w * 1024);
            }
        }
    }

    if (!split) {
        const float inv = 1.0f / l;
        unsigned short* orow = att + (size_t)(b * N_ + qrow) * 1024 + h * 64;
        #pragma unroll
        for (int dt = 0; dt < 4; ++dt) {
            #pragma unroll
            for (int rp = 0; rp < 2; ++rp) {
                const unsigned uu = cvt_pk_bf16(oacc[dt][2 * rp] * inv,
                                                oacc[dt][2 * rp + 1] * inv);
                *reinterpret_cast<unsigned*>(orow + dt * 16 + g * 4 + rp * 2) = uu;
            }
        }
    } else {
        const int slot = (bh * 16 + (qi - 16)) * 2 + half;
        const int rloc = w * 16 + c;
        pml[slot * 64 + rloc] = make_float2(m, l);
        unsigned short* prow = pO + (size_t)slot * 4096 + rloc * 64;
        #pragma unroll
        for (int dt = 0; dt < 4; ++dt) {
            #pragma unroll
            for (int rp = 0; rp < 2; ++rp) {
                const unsigned uu = cvt_pk_bf16(oacc[dt][2 * rp], oacc[dt][2 * rp + 1]);
                *reinterpret_cast<unsigned*>(prow + dt * 16 + g * 4 + rp * 2) = uu;
            }
        }
    }
}

// ---------------- merge split-KV partials ----------------
__global__ __launch_bounds__(256) void attn_merge_kernel(const unsigned short* __restrict__ pO,
                                                         const float2* __restrict__ pml,
                                                         unsigned short* __restrict__ att) {
    const int blk = blockIdx.x;        // 0..511 = bh*16 + qt
    const int bh = blk >> 4;
    const int qt = blk & 15;
    const int qi = 16 + qt;
    const int b = bh >> 4, h = bh & 15;
    const int tid = threadIdx.x;
    const int row = tid >> 2;
    const int d0 = (tid & 3) * 16;
    const int slot0 = (bh * 16 + qt) * 2;
    const float2 ml0 = pml[slot0 * 64 + row];
    const float2 ml1 = pml[(slot0 + 1) * 64 + row];
    const float M = fmaxf(ml0.x, ml1.x);
    const float w0 = exp2_fast(ml0.x - M);
    const float w1 = exp2_fast(ml1.x - M);
    const float invL = 1.0f / (ml0.y * w0 + ml1.y * w1);
    const unsigned short* p0 = pO + (size_t)slot0 * 4096 + row * 64 + d0;
    const unsigned short* p1 = p0 + 4096;
    const int qrow = qi * 64 + row;
    unsigned short* orow = att + (size_t)(b * N_ + qrow) * 1024 + h * 64 + d0;
    #pragma unroll
    for (int j = 0; j < 16; j += 2) {
        const float a0 = (bf2f(p0[j]) * w0 + bf2f(p1[j]) * w1) * invL;
        const float a1 = (bf2f(p0[j + 1]) * w0 + bf2f(p1[j + 1]) * w1) * invL;
        *reinterpret_cast<unsigned*>(orow + j) = cvt_pk_bf16(a0, a1);
    }
}

extern "C" void kernel_launch(void* const* d_in, const int* in_sizes, int n_in,
                              void* d_out, int out_size, void* d_ws, size_t ws_size,
                              hipStream_t stream) {
    const float* x     = (const float*)d_in[0];
    const float* pos   = (const float*)d_in[1];
    const float* gamma = (const float*)d_in[2];
    const float* Wq    = (const float*)d_in[3];
    const float* Wkv   = (const float*)d_in[4];
    const float* Wo    = (const float*)d_in[5];
    const float* bo    = (const float*)d_in[6];
    float* out = (float*)d_out;
    char* ws = (char*)d_ws;

    const size_t MB = 1024 * 1024;
    unsigned short* kb   = (unsigned short*)(ws);             // 8 MB roped K
    unsigned short* qb   = (unsigned short*)(ws + 16 * MB);   // 8 MB roped+scaled Q
    unsigned short* att  = (unsigned short*)(ws + 24 * MB);   // 8 MB attention output
    unsigned short* xb   = (unsigned short*)(ws + 32 * MB);   // 8 MB bf16 x (dead after qkv)
    unsigned short* Wqt  = (unsigned short*)(ws + 40 * MB);   // 2 MB
    unsigned short* Wkvt = (unsigned short*)(ws + 42 * MB);   // 4 MB
    unsigned short* Wot  = (unsigned short*)(ws + 46 * MB);   // 2 MB
    unsigned short* vt   = (unsigned short*)(ws + 48 * MB);   // 8 MB V^T [bh][d][pos]
    float2* tabq         = (float2*)(ws + 56 * MB);           // 1 MB
    float2* tabk         = (float2*)(ws + 57 * MB);           // 1 MB
    float* sv            = (float*)(ws + 58 * MB);            // 16 KB
    unsigned short* pO   = (unsigned short*)(ws + 32 * MB);   // 8.4 MB (overlay, after qkv)
    float2* pml          = (float2*)(ws + 40 * MB + 512 * 1024);  // 512 KB

    prologue_kernel<<<8704, 256, 0, stream>>>(
        x, pos, gamma, Wq, Wkv, Wo, xb, sv, tabq, tabk, Wqt, Wkvt, Wot);

    gemm_qkv_kernel<<<768, 256, 0, stream>>>(
        xb, Wqt, Wkvt, sv, qb, kb, vt, tabq, tabk);

    attn_mfma_kernel<<<1536, 256, 0, stream>>>(qb, kb, vt, att, pO, pml);
    attn_merge_kernel<<<512, 256, 0, stream>>>(pO, pml, att);

    gemm_o_kernel<<<512, 256, 0, stream>>>(att, Wot, bo, out);
}